// Round 12
// baseline (511.264 us; speedup 1.0000x reference)
//
#include <hip/hip_runtime.h>
#include <stdint.h>

#define NN 50000
#define CC 1024
#define HH 128
#define EE 1600000
#define EPSV 1e-8f
#define SCAN_BLKS 196   // ceil(50000/256)

typedef __attribute__((ext_vector_type(8))) short bf16x8;
typedef __attribute__((ext_vector_type(4))) float f32x4;
typedef __attribute__((ext_vector_type(2))) float f32x2;

__device__ __forceinline__ unsigned short f32_to_bf16(float f){
  union { float f; uint32_t u; } cv; cv.f = f;
  uint32_t u = cv.u;
  return (unsigned short)((u + 0x7FFFu + ((u >> 16) & 1u)) >> 16);
}
__device__ __forceinline__ float bf16lo_to_f32(uint32_t w){
  union { uint32_t u; float f; } cv; cv.u = w << 16; return cv.f;
}
__device__ __forceinline__ float bf16hi_to_f32(uint32_t w){
  union { uint32_t u; float f; } cv; cv.u = w & 0xFFFF0000u; return cv.f;
}

// DPP cross-lane add within a 16-lane row (xor1, xor2, ^7-in-8, mirror-16)
#define DPP_ADD(x, ctrl) ((x) + __int_as_float(__builtin_amdgcn_update_dpp(0, __float_as_int(x), (ctrl), 0xF, 0xF, true)))

// async global->LDS 16B DMA (lds dst wave-uniform base + lane*16; global src per-lane)
#define GLOAD_LDS16(g, l) __builtin_amdgcn_global_load_lds( \
    (const __attribute__((address_space(1))) uint32_t*)(g), \
    (__attribute__((address_space(3))) uint32_t*)(l), 16, 0, 0)

// ---------------- merged weight prep: W1T, W2T, Wg1T ----------------

__global__ __launch_bounds__(256) void k_prep_all(
    const float* __restrict__ W1, const float* __restrict__ W2,
    const float* __restrict__ Wg1,
    unsigned short* __restrict__ W1T, unsigned short* __restrict__ W2T,
    unsigned short* __restrict__ Wg1T){
  int idx = blockIdx.x*256 + threadIdx.x;
  if(idx < 131072){                                   // W1T[n][k] = W1[k][n]
    int n = idx >> 10, k = idx & 1023;
    W1T[idx] = f32_to_bf16(W1[k*128 + n]);
  } else if(idx < 131072 + 16384){                    // W2T[n][k] = W2[k][n]
    int i = idx - 131072;
    int n = i >> 7, k = i & 127;
    W2T[i] = f32_to_bf16(W2[k*128 + n]);
  } else if(idx < 131072 + 16384 + 32768){            // Wg1T[c][k]
    int i = idx - 131072 - 16384;
    int c = i >> 7, k = i & 127;
    int row = (c < 128) ? k : (128 + k);
    int col = (c < 128) ? c : (c - 128);
    Wg1T[i] = f32_to_bf16(Wg1[row*128 + col]);
  }
}

// ---------------- CSR build: hist(+rank) + parallel scan + atomic-free fill ----------------

__global__ __launch_bounds__(256) void k_hist(const int* __restrict__ dst,
                                              int* __restrict__ counts,
                                              int* __restrict__ rank){
  int e = blockIdx.x*256 + threadIdx.x;
  if(e < EE) rank[e] = atomicAdd(&counts[dst[e]], 1);
}

__global__ __launch_bounds__(256) void k_scan1(const int* __restrict__ counts,
    int* __restrict__ lexcl, int* __restrict__ bsum){
  __shared__ int buf[256];
  const int t = threadIdx.x, i = blockIdx.x*256 + t;
  int v = (i < NN) ? counts[i] : 0;
  buf[t] = v;
  __syncthreads();
  for(int off = 1; off < 256; off <<= 1){
    int add = (t >= off) ? buf[t-off] : 0;
    __syncthreads();
    buf[t] += add;
    __syncthreads();
  }
  if(i < NN) lexcl[i] = buf[t] - v;
  if(t == 255) bsum[blockIdx.x] = buf[255];
}

__global__ __launch_bounds__(256) void k_scan2(const int* __restrict__ bsum,
    int* __restrict__ bexcl, int* __restrict__ row_ptr){
  __shared__ int buf[256];
  const int t = threadIdx.x;
  int v = (t < SCAN_BLKS) ? bsum[t] : 0;
  buf[t] = v;
  __syncthreads();
  for(int off = 1; off < 256; off <<= 1){
    int add = (t >= off) ? buf[t-off] : 0;
    __syncthreads();
    buf[t] += add;
    __syncthreads();
  }
  if(t < SCAN_BLKS) bexcl[t] = buf[t] - v;
  if(t == 255) row_ptr[NN] = buf[255];
}

__global__ __launch_bounds__(256) void k_scan3(const int* __restrict__ lexcl,
    const int* __restrict__ bexcl, int* __restrict__ row_ptr){
  const int i = blockIdx.x*256 + threadIdx.x;
  if(i >= NN) return;
  row_ptr[i] = lexcl[i] + bexcl[blockIdx.x];
}

// atomic-free fill: p = row_ptr[dst] + rank; writes packed {c, src_bits}
__global__ __launch_bounds__(256) void k_fill(const int* __restrict__ src,
    const int* __restrict__ dst, const float* __restrict__ base_w,
    const float* __restrict__ rho_raw, const int* __restrict__ row_ptr,
    const int* __restrict__ rank, float2* __restrict__ scp){
  int e = blockIdx.x*256 + threadIdx.x;
  if(e >= EE) return;
  int s = src[e], d = dst[e];
  int p = row_ptr[d] + rank[e];
  float rs = 1.f/(1.f + __expf(-rho_raw[s]));
  float rd = 1.f/(1.f + __expf(-rho_raw[d]));
  scp[p] = make_float2(base_w[e]*rs*rd, __int_as_float(s));
}

// ---------------- encoder GEMM1: h1 = relu(X@W1 + b1) -> bf16 [N,128] ----------------
// 32-row M-tile, 3-buffer global_load_lds pipeline with COUNTED vmcnt (T3+T4):
// per step: STAGE(t+2) -> s_waitcnt vmcnt(6) (t+1/t+2 stay in flight) -> raw
// s_barrier -> sched_barrier(0) -> compute tile t -> raw s_barrier.
// Loads survive across barriers; no vmcnt(0) drain in the main loop.

__global__ __launch_bounds__(256) void k_enc1(
    const float* __restrict__ X, const unsigned short* __restrict__ W1T,
    const float* __restrict__ b1, unsigned short* __restrict__ h1)
{
  __shared__ __attribute__((aligned(16))) float          Af[3][32*32];    // 4KB each
  __shared__ __attribute__((aligned(16))) unsigned short Bf[3][128*32];   // 8KB each

  const int t = threadIdx.x, w = t >> 6, lane = t & 63;
  const int rowL = lane & 15, kq = lane >> 4;
  const int wm = w >> 1, wn = w & 1;            // M-half (16 rows), N-half (64 cols)
  const int row0 = blockIdx.x * 32;

  // A: wave w stages LDS rows 8w..8w+7 (64 lanes x 16B = 8 rows x 128B)
  const int a_rl = w*8 + (lane >> 3);
  const int a_cl = lane & 7;
  int agr = row0 + a_rl; if(agr >= NN) agr = NN-1;
  const float* a_src = X + (size_t)agr*1024 + (a_cl ^ (a_rl & 7))*4;
  // B: wave w stages rows 32w..32w+31, two calls of 16 rows
  const int b_rl0 = w*32 + (lane >> 2);
  const int b_cl  = lane & 3;
  const int bkey0 = (b_rl0 ^ (b_rl0 >> 2)) & 3;
  const int bkey1 = ((b_rl0+16) ^ ((b_rl0+16) >> 2)) & 3;
  const unsigned short* b_src0 = W1T + (size_t)b_rl0*1024 + (b_cl ^ bkey0)*8;
  const unsigned short* b_src1 = W1T + (size_t)(b_rl0+16)*1024 + (b_cl ^ bkey1)*8;

  #define STAGE(buf, k0)  do{                                              \
    GLOAD_LDS16(a_src  + (k0), &Af[buf][(w*8)*32]);                        \
    GLOAD_LDS16(b_src0 + (k0), &Bf[buf][(w*32     )*32]);                  \
    GLOAD_LDS16(b_src1 + (k0), &Bf[buf][(w*32 + 16)*32]);                  \
  }while(0)

  f32x4 acc[4] = {};
  const int arow  = wm*16 + rowL;
  const int akey  = rowL & 7;
  const int bkeyR = (rowL ^ (rowL >> 2)) & 3;

  auto COMPUTE = [&](const float* afb, const unsigned short* bfb){
    f32x4 x0 = *(const f32x4*)&afb[arow*32 + (((2*kq  ) ^ akey) << 2)];
    f32x4 x1 = *(const f32x4*)&afb[arow*32 + (((2*kq+1) ^ akey) << 2)];
    union { bf16x8 v; unsigned short s[8]; } pk;
    #pragma unroll
    for(int j = 0; j < 4; j++){ pk.s[j] = f32_to_bf16(x0[j]); pk.s[4+j] = f32_to_bf16(x1[j]); }
    bf16x8 bfr[4];
    #pragma unroll
    for(int nf = 0; nf < 4; nf++){
      const int br = wn*64 + nf*16 + rowL;
      bfr[nf] = *(const bf16x8*)&bfb[br*32 + ((kq ^ bkeyR) << 3)];
    }
    #pragma unroll
    for(int nf = 0; nf < 4; nf++)
      acc[nf] = __builtin_amdgcn_mfma_f32_16x16x32_bf16(pk.v, bfr[nf], acc[nf], 0, 0, 0);
  };

  #define STEP(cbuf, sbuf, sk, vN)  do{                                    \
    if((sk) >= 0) STAGE(sbuf, (sk)*32);                                    \
    asm volatile("s_waitcnt vmcnt(" #vN ")" ::: "memory");                 \
    __builtin_amdgcn_s_barrier();                                          \
    __builtin_amdgcn_sched_barrier(0);                                     \
    COMPUTE(&Af[cbuf][0], &Bf[cbuf][0]);                                   \
    __builtin_amdgcn_s_barrier();                                          \
  }while(0)

  // prologue: tiles 0,1 in flight
  STAGE(0, 0);
  STAGE(1, 32);

  // main: tiles 0..29, statically unrolled by 3 (tile t -> buffer t%3)
  for(int tt = 0; tt < 30; tt += 3){
    STEP(0, 2, tt + 2, 6);      // compute t=tt,   stage tt+2 -> buf2
    STEP(1, 0, tt + 3, 6);      // compute t=tt+1, stage tt+3 -> buf0
    STEP(2, 1, tt + 4, 6);      // compute t=tt+2, stage tt+4 -> buf1
  }
  // epilogue: tiles 30 (buf0), 31 (buf1); drain 3 -> 0
  STEP(0, 0, -1, 3);
  asm volatile("s_waitcnt vmcnt(0)" ::: "memory");
  __builtin_amdgcn_s_barrier();
  __builtin_amdgcn_sched_barrier(0);
  COMPUTE(&Af[1][0], &Bf[1][0]);
  #undef STEP
  #undef STAGE

  // epilogue: bias + relu + bf16 store. C frag: row = kq*4+r, col = rowL.
  #pragma unroll
  for(int nf = 0; nf < 4; nf++){
    const int col = wn*64 + nf*16 + rowL;
    const float bv = b1[col];
    #pragma unroll
    for(int r = 0; r < 4; r++){
      const int gr = row0 + wm*16 + kq*4 + r;
      if(gr < NN) h1[(size_t)gr*128 + col] = f32_to_bf16(fmaxf(acc[nf][r] + bv, 0.f));
    }
  }
}

// ---------------- shared UV phase: [u|v] = h @ Wg1 from swizzled LDS (h AND Wg1T) ----------------

__device__ __forceinline__ void uv_phase2(
    const unsigned short* hs, const unsigned short* wgl, int row0, int wave, int lane,
    const float* __restrict__ bg1,
    unsigned short* __restrict__ UH, float* __restrict__ Vf)
{
  const int rowL = lane & 15, kq = lane >> 4;
  const int r = wave*16 + rowL;
  f32x4 acc[16] = {};
  #pragma unroll
  for(int ks = 0; ks < 4; ks++){
    const int kc = ks*4 + kq;
    bf16x8 a = *(const bf16x8*)&hs[r*128 + ((kc ^ (r & 15)) << 3)];
    #pragma unroll
    for(int nt = 0; nt < 16; nt++){
      bf16x8 b = *(const bf16x8*)&wgl[(nt*16 + rowL)*128 + ((kc ^ rowL) << 3)];
      acc[nt] = __builtin_amdgcn_mfma_f32_16x16x32_bf16(a, b, acc[nt], 0, 0, 0);
    }
  }
  #pragma unroll
  for(int nt = 0; nt < 16; nt++){
    const int col = nt*16 + rowL;
    #pragma unroll
    for(int rr = 0; rr < 4; rr++){
      const int gr = row0 + wave*16 + kq*4 + rr;
      if(gr < NN){
        if(col < 128) UH[(size_t)gr*256 + col] = f32_to_bf16(acc[nt][rr]);
        else          Vf[(size_t)gr*128 + col - 128] = acc[nt][rr] + bg1[col - 128];
      }
    }
  }
}

// ---------------- k_uvA: h = relu(h1@W2T + b2); writes UH=[u|h] bf16, Vf=v+bg1 ----------------

__global__ __launch_bounds__(256) void k_uvA(
    const unsigned short* __restrict__ h1, const unsigned short* __restrict__ W2T,
    const float* __restrict__ b2, const unsigned short* __restrict__ Wg1T,
    const float* __restrict__ bg1, unsigned short* __restrict__ UH,
    float* __restrict__ Vf)
{
  __shared__ __attribute__((aligned(16))) unsigned short hs[64*128];
  __shared__ __attribute__((aligned(16))) unsigned short wgl[256*128];
  const int t = threadIdx.x, wave = t >> 6, lane = t & 63;
  const int rowL = lane & 15, kq = lane >> 4;
  const int row0 = blockIdx.x*64;

  bf16x8 wreg[16];
  #pragma unroll
  for(int i = 0; i < 16; i++)
    wreg[i] = *(const bf16x8*)(Wg1T + (i*256 + t)*8);

  int ar = row0 + wave*16 + rowL; if(ar >= NN) ar = NN-1;
  f32x4 acc[8] = {};
  #pragma unroll
  for(int ks = 0; ks < 4; ks++){
    bf16x8 a = *(const bf16x8*)(h1 + (size_t)ar*128 + ks*32 + kq*8);
    #pragma unroll
    for(int nt = 0; nt < 8; nt++){
      bf16x8 b = *(const bf16x8*)(W2T + (nt*16 + rowL)*128 + ks*32 + kq*8);
      acc[nt] = __builtin_amdgcn_mfma_f32_16x16x32_bf16(a, b, acc[nt], 0, 0, 0);
    }
  }
  #pragma unroll
  for(int nt = 0; nt < 8; nt++){
    const int col = nt*16 + rowL;
    const float bv = b2[col];
    #pragma unroll
    for(int r = 0; r < 4; r++){
      const int rw = wave*16 + kq*4 + r;
      const unsigned short hv = f32_to_bf16(fmaxf(acc[nt][r] + bv, 0.f));
      hs[rw*128 + (((col >> 3) ^ (rw & 15)) << 3) + (col & 7)] = hv;
    }
  }
  #pragma unroll
  for(int i = 0; i < 16; i++){
    const int idx = i*256 + t, row = idx >> 4, c = idx & 15;
    *(bf16x8*)&wgl[row*128 + ((c ^ (row & 15)) << 3)] = wreg[i];
  }
  __syncthreads();
  {
    const int r = t >> 2, gr = row0 + r;
    if(gr < NN){
      #pragma unroll
      for(int j8 = 0; j8 < 4; j8++){
        const int chunk = (t & 3)*4 + j8;
        bf16x8 v = *(const bf16x8*)&hs[r*128 + ((chunk ^ (r & 15)) << 3)];
        *(bf16x8*)&UH[(size_t)gr*256 + 128 + chunk*8] = v;
      }
    }
  }
  uv_phase2(hs, wgl, row0, wave, lane, bg1, UH, Vf);
}

// ---------------- k_uvB: input h f32 (agg output); writes UH=[u|h] bf16, Vf=v+bg1 ----------------

__global__ __launch_bounds__(256) void k_uvB(
    const float* __restrict__ hf, const unsigned short* __restrict__ Wg1T,
    const float* __restrict__ bg1, unsigned short* __restrict__ UH,
    float* __restrict__ Vf)
{
  __shared__ __attribute__((aligned(16))) unsigned short hs[64*128];
  __shared__ __attribute__((aligned(16))) unsigned short wgl[256*128];
  const int t = threadIdx.x, wave = t >> 6, lane = t & 63;
  const int row0 = blockIdx.x*64;

  bf16x8 wreg[16];
  #pragma unroll
  for(int i = 0; i < 16; i++)
    wreg[i] = *(const bf16x8*)(Wg1T + (i*256 + t)*8);

  {
    const int r = t >> 2, gr0 = row0 + r;
    const int gr = (gr0 < NN) ? gr0 : NN-1;
    const float* p = hf + (size_t)gr*128 + (t & 3)*32;
    #pragma unroll
    for(int j8 = 0; j8 < 4; j8++){
      f32x4 v0 = *(const f32x4*)(p + j8*8);
      f32x4 v1 = *(const f32x4*)(p + j8*8 + 4);
      union { bf16x8 v; unsigned short s[8]; } pk;
      #pragma unroll
      for(int j = 0; j < 4; j++){ pk.s[j] = f32_to_bf16(v0[j]); pk.s[4+j] = f32_to_bf16(v1[j]); }
      const int chunk = (t & 3)*4 + j8;
      *(bf16x8*)&hs[r*128 + ((chunk ^ (r & 15)) << 3)] = pk.v;
      if(gr0 < NN) *(bf16x8*)&UH[(size_t)gr0*256 + 128 + chunk*8] = pk.v;
    }
  }
  #pragma unroll
  for(int i = 0; i < 16; i++){
    const int idx = i*256 + t, row = idx >> 4, c = idx & 15;
    *(bf16x8*)&wgl[row*128 + ((c ^ (row & 15)) << 3)] = wreg[i];
  }
  __syncthreads();
  uv_phase2(hs, wgl, row0, wave, lane & 63, bg1, UH, Vf);
}

// ---------------- fused gate + aggregation, CSR order, one wave per dst node ----------------
// gate: 8 edges/iter (2 per 16-lane group in flight), DPP row reduction,
// depth-1 pair prefetch, packed {c,src} metadata.

__global__ __launch_bounds__(256) void k_gate_agg(
    const unsigned short* __restrict__ UH, const float* __restrict__ Vf,
    const int* __restrict__ row_ptr, const float2* __restrict__ scp,
    const float* __restrict__ Wg2, const float* __restrict__ bg2p,
    float* __restrict__ out_f32)
{
  __shared__ float2 ws_s[4][64];
  const int wv = threadIdx.x >> 6, lane = threadIdx.x & 63;
  const int gw = blockIdx.x*4 + wv;
  if(gw >= NN) return;
  const int eq = lane >> 4, li = lane & 15;

  f32x4 va = *(const f32x4*)(Vf + (size_t)gw*128 + li*8);
  f32x4 vb = *(const f32x4*)(Vf + (size_t)gw*128 + li*8 + 4);
  f32x4 wa = *(const f32x4*)(Wg2 + li*8);
  f32x4 wb = *(const f32x4*)(Wg2 + li*8 + 4);
  const float vch[8]  = {va[0],va[1],va[2],va[3],vb[0],vb[1],vb[2],vb[3]};
  const float w2ch[8] = {wa[0],wa[1],wa[2],wa[3],wb[0],wb[1],wb[2],wb[3]};
  const float bg2v = bg2p[0];

  const int beg = row_ptr[gw], end = row_ptr[gw+1];
  float a0 = 0.f, a1 = 0.f, wsum = 0.f;

  for(int base = beg; base < end; base += 64){
    const int nb = min(64, end - base);

    float2 sc_c0, sc_c1; bf16x8 u_c0, u_c1;
    {
      const int i0 = (eq     < nb) ? eq     : 0;
      const int i1 = (4 + eq < nb) ? 4 + eq : 0;
      sc_c0 = scp[base + i0]; sc_c1 = scp[base + i1];
      u_c0 = *(const bf16x8*)&UH[(uint32_t)__float_as_int(sc_c0.y)*256u + li*8];
      u_c1 = *(const bf16x8*)&UH[(uint32_t)__float_as_int(sc_c1.y)*256u + li*8];
    }
    for(int q = 0; q < nb; q += 8){
      float2 sc_n0 = sc_c0, sc_n1 = sc_c1; bf16x8 u_n0 = u_c0, u_n1 = u_c1;
      if(q + 8 < nb){
        const int i0 = (q + 8  + eq < nb) ? q + 8  + eq : 0;
        const int i1 = (q + 12 + eq < nb) ? q + 12 + eq : 0;
        sc_n0 = scp[base + i0]; sc_n1 = scp[base + i1];
        u_n0 = *(const bf16x8*)&UH[(uint32_t)__float_as_int(sc_n0.y)*256u + li*8];
        u_n1 = *(const bf16x8*)&UH[(uint32_t)__float_as_int(sc_n1.y)*256u + li*8];
      }
      { // edge A: idx = q + eq
        union { bf16x8 v; uint32_t u32[4]; } uu; uu.v = u_c0;
        float tacc = 0.f;
        #pragma unroll
        for(int p = 0; p < 4; p++){
          const uint32_t w2b = uu.u32[p];
          tacc += fmaxf(bf16lo_to_f32(w2b) + vch[2*p],   0.f) * w2ch[2*p];
          tacc += fmaxf(bf16hi_to_f32(w2b) + vch[2*p+1], 0.f) * w2ch[2*p+1];
        }
        tacc = DPP_ADD(tacc, 0xB1);
        tacc = DPP_ADD(tacc, 0x4E);
        tacc = DPP_ADD(tacc, 0x141);
        tacc = DPP_ADD(tacc, 0x140);
        const float g = 1.f/(1.f + __expf(-(tacc + bg2v)));
        const int idx = q + eq;
        if(li == 0 && idx < nb) ws_s[wv][idx] = make_float2(sc_c0.x*g, sc_c0.y);
      }
      { // edge B: idx = q + 4 + eq
        union { bf16x8 v; uint32_t u32[4]; } uu; uu.v = u_c1;
        float tacc = 0.f;
        #pragma unroll
        for(int p = 0; p < 4; p++){
          const uint32_t w2b = uu.u32[p];
          tacc += fmaxf(bf16lo_to_f32(w2b) + vch[2*p],   0.f) * w2ch[2*p];
          tacc += fmaxf(bf16hi_to_f32(w2b) + vch[2*p+1], 0.f) * w2ch[2*p+1];
        }
        tacc = DPP_ADD(tacc, 0xB1);
        tacc = DPP_ADD(tacc, 0x4E);
        tacc = DPP_ADD(tacc, 0x141);
        tacc = DPP_ADD(tacc, 0x140);
        const float g = 1.f/(1.f + __expf(-(tacc + bg2v)));
        const int idx = q + 4 + eq;
        if(li == 0 && idx < nb) ws_s[wv][idx] = make_float2(sc_c1.x*g, sc_c1.y);
      }
      sc_c0 = sc_n0; sc_c1 = sc_n1; u_c0 = u_n0; u_c1 = u_n1;
    }

    #pragma unroll 8
    for(int j = 0; j < nb; j++){
      const float2 p = ws_s[wv][j];
      const float w  = p.x;
      const uint32_t s = (uint32_t)__float_as_int(p.y);
      const uint32_t hw = *(const uint32_t*)&UH[s*256u + 128u + lane*2];
      a0 += w*bf16lo_to_f32(hw);
      a1 += w*bf16hi_to_f32(hw);
      wsum += w;
    }
  }
  const float inv = 1.f/(wsum + EPSV);
  const size_t o = (size_t)gw*128 + lane*2;
  *(f32x2*)&out_f32[o] = (f32x2){a0*inv, a1*inv};
}

// ---------------- launch ----------------

extern "C" void kernel_launch(void* const* d_in, const int* in_sizes, int n_in,
                              void* d_out, int out_size, void* d_ws, size_t ws_size,
                              hipStream_t stream) {
  (void)in_sizes; (void)n_in; (void)out_size; (void)ws_size;
  const float* X      = (const float*)d_in[0];
  const int*   src    = (const int*)d_in[1];
  const int*   dst    = (const int*)d_in[2];
  const float* base_w = (const float*)d_in[3];
  const float* W1     = (const float*)d_in[4];
  const float* b1     = (const float*)d_in[5];
  const float* W2     = (const float*)d_in[6];
  const float* b2     = (const float*)d_in[7];
  const float* Wg1    = (const float*)d_in[8];
  const float* bg1    = (const float*)d_in[9];
  const float* Wg2    = (const float*)d_in[10];
  const float* bg2    = (const float*)d_in[11];
  const float* rho    = (const float*)d_in[12];

  char* ws = (char*)d_ws;
  size_t off = 0;
  auto alloc = [&](size_t bytes)->char*{ char* p = ws + off; off += (bytes + 255) & ~(size_t)255; return p; };
  unsigned short* W1T      = (unsigned short*)alloc((size_t)1024*128*2);
  unsigned short* W2T      = (unsigned short*)alloc((size_t)128*128*2);
  unsigned short* Wg1T     = (unsigned short*)alloc((size_t)256*128*2);
  int*            rank     = (int*)alloc((size_t)EE*4);
  float2*         scp      = (float2*)alloc((size_t)EE*8);
  int*            row_ptr  = (int*)alloc((size_t)(NN+1)*4);
  int*            counts   = (int*)alloc((size_t)NN*4);
  int*            lexcl    = (int*)alloc((size_t)NN*4);
  int*            bsum     = (int*)alloc((size_t)256*4);
  int*            bexcl    = (int*)alloc((size_t)256*4);
  unsigned short* h1       = (unsigned short*)alloc((size_t)NN*128*2);
  unsigned short* UH       = (unsigned short*)alloc((size_t)NN*256*2);
  float*          Vf       = (float*)alloc((size_t)NN*128*4);
  float*          hf_B     = (float*)alloc((size_t)NN*128*4);

  hipMemsetAsync(counts, 0, (size_t)NN*4, stream);
  k_prep_all<<<704, 256, 0, stream>>>(W1, W2, Wg1, W1T, W2T, Wg1T);
  k_hist<<<EE/256, 256, 0, stream>>>(dst, counts, rank);
  k_scan1<<<SCAN_BLKS, 256, 0, stream>>>(counts, lexcl, bsum);
  k_scan2<<<1, 256, 0, stream>>>(bsum, bexcl, row_ptr);
  k_scan3<<<SCAN_BLKS, 256, 0, stream>>>(lexcl, bexcl, row_ptr);
  k_fill<<<EE/256, 256, 0, stream>>>(src, dst, base_w, rho, row_ptr, rank, scp);

  k_enc1<<<1563, 256, 0, stream>>>(X, W1T, b1, h1);

  // layer 1
  k_uvA<<<782, 256, 0, stream>>>(h1, W2T, b2, Wg1T, bg1, UH, Vf);
  k_gate_agg<<<12500, 256, 0, stream>>>(UH, Vf, row_ptr, scp, Wg2, bg2, hf_B);
  // layer 2
  k_uvB<<<782, 256, 0, stream>>>(hf_B, Wg1T, bg1, UH, Vf);
  k_gate_agg<<<12500, 256, 0, stream>>>(UH, Vf, row_ptr, scp, Wg2, bg2, (float*)d_out);
}

// Round 13
// 509.990 us; speedup vs baseline: 1.0025x; 1.0025x over previous
//
#include <hip/hip_runtime.h>
#include <stdint.h>

#define NN 50000
#define CC 1024
#define HH 128
#define EE 1600000
#define EPSV 1e-8f
#define NSTRIPE 8
#define STRIPE_N 6250              // nodes per stripe (3.2MB of UH each)
#define NBUCK (NN*NSTRIPE)         // 400000 (dst,stripe) buckets
#define SCAN_BLKS 1563             // ceil(NBUCK/256)

typedef __attribute__((ext_vector_type(8))) short bf16x8;
typedef __attribute__((ext_vector_type(4))) float f32x4;
typedef __attribute__((ext_vector_type(2))) float f32x2;

__device__ __forceinline__ unsigned short f32_to_bf16(float f){
  union { float f; uint32_t u; } cv; cv.f = f;
  uint32_t u = cv.u;
  return (unsigned short)((u + 0x7FFFu + ((u >> 16) & 1u)) >> 16);
}
__device__ __forceinline__ float bf16lo_to_f32(uint32_t w){
  union { uint32_t u; float f; } cv; cv.u = w << 16; return cv.f;
}
__device__ __forceinline__ float bf16hi_to_f32(uint32_t w){
  union { uint32_t u; float f; } cv; cv.u = w & 0xFFFF0000u; return cv.f;
}

// DPP cross-lane add within a 16-lane row (xor1, xor2, ^7-in-8, mirror-16)
#define DPP_ADD(x, ctrl) ((x) + __int_as_float(__builtin_amdgcn_update_dpp(0, __float_as_int(x), (ctrl), 0xF, 0xF, true)))

// async global->LDS 16B DMA (lds dst wave-uniform base + lane*16; global src per-lane)
#define GLOAD_LDS16(g, l) __builtin_amdgcn_global_load_lds( \
    (const __attribute__((address_space(1))) uint32_t*)(g), \
    (__attribute__((address_space(3))) uint32_t*)(l), 16, 0, 0)

// ---------------- merged weight prep: W1T, W2T, Wg1T ----------------

__global__ __launch_bounds__(256) void k_prep_all(
    const float* __restrict__ W1, const float* __restrict__ W2,
    const float* __restrict__ Wg1,
    unsigned short* __restrict__ W1T, unsigned short* __restrict__ W2T,
    unsigned short* __restrict__ Wg1T){
  int idx = blockIdx.x*256 + threadIdx.x;
  if(idx < 131072){                                   // W1T[n][k] = W1[k][n]
    int n = idx >> 10, k = idx & 1023;
    W1T[idx] = f32_to_bf16(W1[k*128 + n]);
  } else if(idx < 131072 + 16384){                    // W2T[n][k] = W2[k][n]
    int i = idx - 131072;
    int n = i >> 7, k = i & 127;
    W2T[i] = f32_to_bf16(W2[k*128 + n]);
  } else if(idx < 131072 + 16384 + 32768){            // Wg1T[c][k]
    int i = idx - 131072 - 16384;
    int c = i >> 7, k = i & 127;
    int row = (c < 128) ? k : (128 + k);
    int col = (c < 128) ? c : (c - 128);
    Wg1T[i] = f32_to_bf16(Wg1[row*128 + col]);
  }
}

// ---------------- CSR build over (dst, src-stripe) buckets ----------------
// key = dst*8 + src/6250. Edges land sorted by src-stripe within each dst ->
// gate_agg's gather working set collapses to ~1-2 stripes (3.2MB each, L2-sized).

__global__ __launch_bounds__(256) void k_hist(const int* __restrict__ src,
    const int* __restrict__ dst, int* __restrict__ counts,
    int* __restrict__ rank){
  int e = blockIdx.x*256 + threadIdx.x;
  if(e >= EE) return;
  int key = dst[e]*NSTRIPE + (int)((unsigned)src[e] / STRIPE_N);
  rank[e] = atomicAdd(&counts[key], 1);
}

__global__ __launch_bounds__(256) void k_scan1(const int* __restrict__ counts,
    int* __restrict__ lexcl, int* __restrict__ bsum){
  __shared__ int buf[256];
  const int t = threadIdx.x, i = blockIdx.x*256 + t;
  int v = (i < NBUCK) ? counts[i] : 0;
  buf[t] = v;
  __syncthreads();
  for(int off = 1; off < 256; off <<= 1){
    int add = (t >= off) ? buf[t-off] : 0;
    __syncthreads();
    buf[t] += add;
    __syncthreads();
  }
  if(i < NBUCK) lexcl[i] = buf[t] - v;
  if(t == 255) bsum[blockIdx.x] = buf[255];
}

// exclusive scan over the 1563 block sums (single 1024-thread block, 2 chunks)
__global__ __launch_bounds__(1024) void k_scan_mid(const int* __restrict__ bsum,
    int* __restrict__ bexcl){
  __shared__ int buf[1024];
  __shared__ int carry_s;
  const int t = threadIdx.x;
  if(t == 0) carry_s = 0;
  __syncthreads();
  for(int base = 0; base < SCAN_BLKS; base += 1024){
    int v = (base+t < SCAN_BLKS) ? bsum[base+t] : 0;
    buf[t] = v;
    __syncthreads();
    for(int off = 1; off < 1024; off <<= 1){
      int add = (t >= off) ? buf[t-off] : 0;
      __syncthreads();
      buf[t] += add;
      __syncthreads();
    }
    int carry = carry_s;
    if(base+t < SCAN_BLKS) bexcl[base+t] = carry + buf[t] - v;
    __syncthreads();
    if(t == 1023) carry_s = carry + buf[1023];
    __syncthreads();
  }
}

__global__ __launch_bounds__(256) void k_scan3(const int* __restrict__ lexcl,
    const int* __restrict__ bexcl, int* __restrict__ bptr){
  const int i = blockIdx.x*256 + threadIdx.x;
  if(i < NBUCK) bptr[i] = lexcl[i] + bexcl[blockIdx.x];
  if(i == 0) bptr[NBUCK] = EE;
}

// atomic-free fill: p = bptr[key] + rank; writes packed {c, src_bits}
__global__ __launch_bounds__(256) void k_fill(const int* __restrict__ src,
    const int* __restrict__ dst, const float* __restrict__ base_w,
    const float* __restrict__ rho_raw, const int* __restrict__ bptr,
    const int* __restrict__ rank, float2* __restrict__ scp){
  int e = blockIdx.x*256 + threadIdx.x;
  if(e >= EE) return;
  int s = src[e], d = dst[e];
  int key = d*NSTRIPE + (int)((unsigned)s / STRIPE_N);
  int p = bptr[key] + rank[e];
  float rs = 1.f/(1.f + __expf(-rho_raw[s]));
  float rd = 1.f/(1.f + __expf(-rho_raw[d]));
  scp[p] = make_float2(base_w[e]*rs*rd, __int_as_float(s));
}

// ---------------- encoder GEMM1: h1 = relu(X@W1 + b1) -> bf16 [N,128] ----------------
// 32-row M-tile, 3-buffer global_load_lds pipeline with counted vmcnt.
// (Known-flat at ~120us across schedules -- memory-stream-bound; parked.)

__global__ __launch_bounds__(256) void k_enc1(
    const float* __restrict__ X, const unsigned short* __restrict__ W1T,
    const float* __restrict__ b1, unsigned short* __restrict__ h1)
{
  __shared__ __attribute__((aligned(16))) float          Af[3][32*32];    // 4KB each
  __shared__ __attribute__((aligned(16))) unsigned short Bf[3][128*32];   // 8KB each

  const int t = threadIdx.x, w = t >> 6, lane = t & 63;
  const int rowL = lane & 15, kq = lane >> 4;
  const int wm = w >> 1, wn = w & 1;
  const int row0 = blockIdx.x * 32;

  const int a_rl = w*8 + (lane >> 3);
  const int a_cl = lane & 7;
  int agr = row0 + a_rl; if(agr >= NN) agr = NN-1;
  const float* a_src = X + (size_t)agr*1024 + (a_cl ^ (a_rl & 7))*4;
  const int b_rl0 = w*32 + (lane >> 2);
  const int b_cl  = lane & 3;
  const int bkey0 = (b_rl0 ^ (b_rl0 >> 2)) & 3;
  const int bkey1 = ((b_rl0+16) ^ ((b_rl0+16) >> 2)) & 3;
  const unsigned short* b_src0 = W1T + (size_t)b_rl0*1024 + (b_cl ^ bkey0)*8;
  const unsigned short* b_src1 = W1T + (size_t)(b_rl0+16)*1024 + (b_cl ^ bkey1)*8;

  #define STAGE(buf, k0)  do{                                              \
    GLOAD_LDS16(a_src  + (k0), &Af[buf][(w*8)*32]);                        \
    GLOAD_LDS16(b_src0 + (k0), &Bf[buf][(w*32     )*32]);                  \
    GLOAD_LDS16(b_src1 + (k0), &Bf[buf][(w*32 + 16)*32]);                  \
  }while(0)

  f32x4 acc[4] = {};
  const int arow  = wm*16 + rowL;
  const int akey  = rowL & 7;
  const int bkeyR = (rowL ^ (rowL >> 2)) & 3;

  auto COMPUTE = [&](const float* afb, const unsigned short* bfb){
    f32x4 x0 = *(const f32x4*)&afb[arow*32 + (((2*kq  ) ^ akey) << 2)];
    f32x4 x1 = *(const f32x4*)&afb[arow*32 + (((2*kq+1) ^ akey) << 2)];
    union { bf16x8 v; unsigned short s[8]; } pk;
    #pragma unroll
    for(int j = 0; j < 4; j++){ pk.s[j] = f32_to_bf16(x0[j]); pk.s[4+j] = f32_to_bf16(x1[j]); }
    bf16x8 bfr[4];
    #pragma unroll
    for(int nf = 0; nf < 4; nf++){
      const int br = wn*64 + nf*16 + rowL;
      bfr[nf] = *(const bf16x8*)&bfb[br*32 + ((kq ^ bkeyR) << 3)];
    }
    #pragma unroll
    for(int nf = 0; nf < 4; nf++)
      acc[nf] = __builtin_amdgcn_mfma_f32_16x16x32_bf16(pk.v, bfr[nf], acc[nf], 0, 0, 0);
  };

  #define STEP(cbuf, sbuf, sk, vN)  do{                                    \
    if((sk) >= 0) STAGE(sbuf, (sk)*32);                                    \
    asm volatile("s_waitcnt vmcnt(" #vN ")" ::: "memory");                 \
    __builtin_amdgcn_s_barrier();                                          \
    __builtin_amdgcn_sched_barrier(0);                                     \
    COMPUTE(&Af[cbuf][0], &Bf[cbuf][0]);                                   \
    __builtin_amdgcn_s_barrier();                                          \
  }while(0)

  STAGE(0, 0);
  STAGE(1, 32);

  for(int tt = 0; tt < 30; tt += 3){
    STEP(0, 2, tt + 2, 6);
    STEP(1, 0, tt + 3, 6);
    STEP(2, 1, tt + 4, 6);
  }
  STEP(0, 0, -1, 3);
  asm volatile("s_waitcnt vmcnt(0)" ::: "memory");
  __builtin_amdgcn_s_barrier();
  __builtin_amdgcn_sched_barrier(0);
  COMPUTE(&Af[1][0], &Bf[1][0]);
  #undef STEP
  #undef STAGE

  #pragma unroll
  for(int nf = 0; nf < 4; nf++){
    const int col = wn*64 + nf*16 + rowL;
    const float bv = b1[col];
    #pragma unroll
    for(int r = 0; r < 4; r++){
      const int gr = row0 + wm*16 + kq*4 + r;
      if(gr < NN) h1[(size_t)gr*128 + col] = f32_to_bf16(fmaxf(acc[nf][r] + bv, 0.f));
    }
  }
}

// ---------------- shared UV phase: [u|v] = h @ Wg1 from swizzled LDS (h AND Wg1T) ----------------

__device__ __forceinline__ void uv_phase2(
    const unsigned short* hs, const unsigned short* wgl, int row0, int wave, int lane,
    const float* __restrict__ bg1,
    unsigned short* __restrict__ UH, float* __restrict__ Vf)
{
  const int rowL = lane & 15, kq = lane >> 4;
  const int r = wave*16 + rowL;
  f32x4 acc[16] = {};
  #pragma unroll
  for(int ks = 0; ks < 4; ks++){
    const int kc = ks*4 + kq;
    bf16x8 a = *(const bf16x8*)&hs[r*128 + ((kc ^ (r & 15)) << 3)];
    #pragma unroll
    for(int nt = 0; nt < 16; nt++){
      bf16x8 b = *(const bf16x8*)&wgl[(nt*16 + rowL)*128 + ((kc ^ rowL) << 3)];
      acc[nt] = __builtin_amdgcn_mfma_f32_16x16x32_bf16(a, b, acc[nt], 0, 0, 0);
    }
  }
  #pragma unroll
  for(int nt = 0; nt < 16; nt++){
    const int col = nt*16 + rowL;
    #pragma unroll
    for(int rr = 0; rr < 4; rr++){
      const int gr = row0 + wave*16 + kq*4 + rr;
      if(gr < NN){
        if(col < 128) UH[(size_t)gr*256 + col] = f32_to_bf16(acc[nt][rr]);
        else          Vf[(size_t)gr*128 + col - 128] = acc[nt][rr] + bg1[col - 128];
      }
    }
  }
}

// ---------------- k_uvA: h = relu(h1@W2T + b2); writes UH=[u|h] bf16, Vf=v+bg1 ----------------

__global__ __launch_bounds__(256) void k_uvA(
    const unsigned short* __restrict__ h1, const unsigned short* __restrict__ W2T,
    const float* __restrict__ b2, const unsigned short* __restrict__ Wg1T,
    const float* __restrict__ bg1, unsigned short* __restrict__ UH,
    float* __restrict__ Vf)
{
  __shared__ __attribute__((aligned(16))) unsigned short hs[64*128];
  __shared__ __attribute__((aligned(16))) unsigned short wgl[256*128];
  const int t = threadIdx.x, wave = t >> 6, lane = t & 63;
  const int rowL = lane & 15, kq = lane >> 4;
  const int row0 = blockIdx.x*64;

  bf16x8 wreg[16];
  #pragma unroll
  for(int i = 0; i < 16; i++)
    wreg[i] = *(const bf16x8*)(Wg1T + (i*256 + t)*8);

  int ar = row0 + wave*16 + rowL; if(ar >= NN) ar = NN-1;
  f32x4 acc[8] = {};
  #pragma unroll
  for(int ks = 0; ks < 4; ks++){
    bf16x8 a = *(const bf16x8*)(h1 + (size_t)ar*128 + ks*32 + kq*8);
    #pragma unroll
    for(int nt = 0; nt < 8; nt++){
      bf16x8 b = *(const bf16x8*)(W2T + (nt*16 + rowL)*128 + ks*32 + kq*8);
      acc[nt] = __builtin_amdgcn_mfma_f32_16x16x32_bf16(a, b, acc[nt], 0, 0, 0);
    }
  }
  #pragma unroll
  for(int nt = 0; nt < 8; nt++){
    const int col = nt*16 + rowL;
    const float bv = b2[col];
    #pragma unroll
    for(int r = 0; r < 4; r++){
      const int rw = wave*16 + kq*4 + r;
      const unsigned short hv = f32_to_bf16(fmaxf(acc[nt][r] + bv, 0.f));
      hs[rw*128 + (((col >> 3) ^ (rw & 15)) << 3) + (col & 7)] = hv;
    }
  }
  #pragma unroll
  for(int i = 0; i < 16; i++){
    const int idx = i*256 + t, row = idx >> 4, c = idx & 15;
    *(bf16x8*)&wgl[row*128 + ((c ^ (row & 15)) << 3)] = wreg[i];
  }
  __syncthreads();
  {
    const int r = t >> 2, gr = row0 + r;
    if(gr < NN){
      #pragma unroll
      for(int j8 = 0; j8 < 4; j8++){
        const int chunk = (t & 3)*4 + j8;
        bf16x8 v = *(const bf16x8*)&hs[r*128 + ((chunk ^ (r & 15)) << 3)];
        *(bf16x8*)&UH[(size_t)gr*256 + 128 + chunk*8] = v;
      }
    }
  }
  uv_phase2(hs, wgl, row0, wave, lane, bg1, UH, Vf);
}

// ---------------- k_uvB: input h f32 (agg output); writes UH=[u|h] bf16, Vf=v+bg1 ----------------

__global__ __launch_bounds__(256) void k_uvB(
    const float* __restrict__ hf, const unsigned short* __restrict__ Wg1T,
    const float* __restrict__ bg1, unsigned short* __restrict__ UH,
    float* __restrict__ Vf)
{
  __shared__ __attribute__((aligned(16))) unsigned short hs[64*128];
  __shared__ __attribute__((aligned(16))) unsigned short wgl[256*128];
  const int t = threadIdx.x, wave = t >> 6, lane = t & 63;
  const int row0 = blockIdx.x*64;

  bf16x8 wreg[16];
  #pragma unroll
  for(int i = 0; i < 16; i++)
    wreg[i] = *(const bf16x8*)(Wg1T + (i*256 + t)*8);

  {
    const int r = t >> 2, gr0 = row0 + r;
    const int gr = (gr0 < NN) ? gr0 : NN-1;
    const float* p = hf + (size_t)gr*128 + (t & 3)*32;
    #pragma unroll
    for(int j8 = 0; j8 < 4; j8++){
      f32x4 v0 = *(const f32x4*)(p + j8*8);
      f32x4 v1 = *(const f32x4*)(p + j8*8 + 4);
      union { bf16x8 v; unsigned short s[8]; } pk;
      #pragma unroll
      for(int j = 0; j < 4; j++){ pk.s[j] = f32_to_bf16(v0[j]); pk.s[4+j] = f32_to_bf16(v1[j]); }
      const int chunk = (t & 3)*4 + j8;
      *(bf16x8*)&hs[r*128 + ((chunk ^ (r & 15)) << 3)] = pk.v;
      if(gr0 < NN) *(bf16x8*)&UH[(size_t)gr0*256 + 128 + chunk*8] = pk.v;
    }
  }
  #pragma unroll
  for(int i = 0; i < 16; i++){
    const int idx = i*256 + t, row = idx >> 4, c = idx & 15;
    *(bf16x8*)&wgl[row*128 + ((c ^ (row & 15)) << 3)] = wreg[i];
  }
  __syncthreads();
  uv_phase2(hs, wgl, row0, wave, lane & 63, bg1, UH, Vf);
}

// ---------------- fused gate + aggregation, stripe-sorted CSR, one wave per dst ----------------
// Edge range for node gw: [bptr[gw*8], bptr[gw*8+8]) -- edges sorted by src-stripe,
// so resident blocks' gathers concentrate in ~1-2 L2-sized UH stripes at a time.

__global__ __launch_bounds__(256) void k_gate_agg(
    const unsigned short* __restrict__ UH, const float* __restrict__ Vf,
    const int* __restrict__ bptr, const float2* __restrict__ scp,
    const float* __restrict__ Wg2, const float* __restrict__ bg2p,
    float* __restrict__ out_f32)
{
  __shared__ float2 ws_s[4][64];
  const int wv = threadIdx.x >> 6, lane = threadIdx.x & 63;
  const int gw = blockIdx.x*4 + wv;
  if(gw >= NN) return;
  const int eq = lane >> 4, li = lane & 15;

  f32x4 va = *(const f32x4*)(Vf + (size_t)gw*128 + li*8);
  f32x4 vb = *(const f32x4*)(Vf + (size_t)gw*128 + li*8 + 4);
  f32x4 wa = *(const f32x4*)(Wg2 + li*8);
  f32x4 wb = *(const f32x4*)(Wg2 + li*8 + 4);
  const float vch[8]  = {va[0],va[1],va[2],va[3],vb[0],vb[1],vb[2],vb[3]};
  const float w2ch[8] = {wa[0],wa[1],wa[2],wa[3],wb[0],wb[1],wb[2],wb[3]};
  const float bg2v = bg2p[0];

  const int beg = bptr[gw*NSTRIPE], end = bptr[gw*NSTRIPE + NSTRIPE];
  float a0 = 0.f, a1 = 0.f, wsum = 0.f;

  for(int base = beg; base < end; base += 64){
    const int nb = min(64, end - base);

    float2 sc_c0, sc_c1; bf16x8 u_c0, u_c1;
    {
      const int i0 = (eq     < nb) ? eq     : 0;
      const int i1 = (4 + eq < nb) ? 4 + eq : 0;
      sc_c0 = scp[base + i0]; sc_c1 = scp[base + i1];
      u_c0 = *(const bf16x8*)&UH[(uint32_t)__float_as_int(sc_c0.y)*256u + li*8];
      u_c1 = *(const bf16x8*)&UH[(uint32_t)__float_as_int(sc_c1.y)*256u + li*8];
    }
    for(int q = 0; q < nb; q += 8){
      float2 sc_n0 = sc_c0, sc_n1 = sc_c1; bf16x8 u_n0 = u_c0, u_n1 = u_c1;
      if(q + 8 < nb){
        const int i0 = (q + 8  + eq < nb) ? q + 8  + eq : 0;
        const int i1 = (q + 12 + eq < nb) ? q + 12 + eq : 0;
        sc_n0 = scp[base + i0]; sc_n1 = scp[base + i1];
        u_n0 = *(const bf16x8*)&UH[(uint32_t)__float_as_int(sc_n0.y)*256u + li*8];
        u_n1 = *(const bf16x8*)&UH[(uint32_t)__float_as_int(sc_n1.y)*256u + li*8];
      }
      { // edge A: idx = q + eq
        union { bf16x8 v; uint32_t u32[4]; } uu; uu.v = u_c0;
        float tacc = 0.f;
        #pragma unroll
        for(int p = 0; p < 4; p++){
          const uint32_t w2b = uu.u32[p];
          tacc += fmaxf(bf16lo_to_f32(w2b) + vch[2*p],   0.f) * w2ch[2*p];
          tacc += fmaxf(bf16hi_to_f32(w2b) + vch[2*p+1], 0.f) * w2ch[2*p+1];
        }
        tacc = DPP_ADD(tacc, 0xB1);
        tacc = DPP_ADD(tacc, 0x4E);
        tacc = DPP_ADD(tacc, 0x141);
        tacc = DPP_ADD(tacc, 0x140);
        const float g = 1.f/(1.f + __expf(-(tacc + bg2v)));
        const int idx = q + eq;
        if(li == 0 && idx < nb) ws_s[wv][idx] = make_float2(sc_c0.x*g, sc_c0.y);
      }
      { // edge B: idx = q + 4 + eq
        union { bf16x8 v; uint32_t u32[4]; } uu; uu.v = u_c1;
        float tacc = 0.f;
        #pragma unroll
        for(int p = 0; p < 4; p++){
          const uint32_t w2b = uu.u32[p];
          tacc += fmaxf(bf16lo_to_f32(w2b) + vch[2*p],   0.f) * w2ch[2*p];
          tacc += fmaxf(bf16hi_to_f32(w2b) + vch[2*p+1], 0.f) * w2ch[2*p+1];
        }
        tacc = DPP_ADD(tacc, 0xB1);
        tacc = DPP_ADD(tacc, 0x4E);
        tacc = DPP_ADD(tacc, 0x141);
        tacc = DPP_ADD(tacc, 0x140);
        const float g = 1.f/(1.f + __expf(-(tacc + bg2v)));
        const int idx = q + 4 + eq;
        if(li == 0 && idx < nb) ws_s[wv][idx] = make_float2(sc_c1.x*g, sc_c1.y);
      }
      sc_c0 = sc_n0; sc_c1 = sc_n1; u_c0 = u_n0; u_c1 = u_n1;
    }

    #pragma unroll 8
    for(int j = 0; j < nb; j++){
      const float2 p = ws_s[wv][j];
      const float w  = p.x;
      const uint32_t s = (uint32_t)__float_as_int(p.y);
      const uint32_t hw = *(const uint32_t*)&UH[s*256u + 128u + lane*2];
      a0 += w*bf16lo_to_f32(hw);
      a1 += w*bf16hi_to_f32(hw);
      wsum += w;
    }
  }
  const float inv = 1.f/(wsum + EPSV);
  const size_t o = (size_t)gw*128 + lane*2;
  *(f32x2*)&out_f32[o] = (f32x2){a0*inv, a1*inv};
}

// ---------------- launch ----------------

extern "C" void kernel_launch(void* const* d_in, const int* in_sizes, int n_in,
                              void* d_out, int out_size, void* d_ws, size_t ws_size,
                              hipStream_t stream) {
  (void)in_sizes; (void)n_in; (void)out_size; (void)ws_size;
  const float* X      = (const float*)d_in[0];
  const int*   src    = (const int*)d_in[1];
  const int*   dst    = (const int*)d_in[2];
  const float* base_w = (const float*)d_in[3];
  const float* W1     = (const float*)d_in[4];
  const float* b1     = (const float*)d_in[5];
  const float* W2     = (const float*)d_in[6];
  const float* b2     = (const float*)d_in[7];
  const float* Wg1    = (const float*)d_in[8];
  const float* bg1    = (const float*)d_in[9];
  const float* Wg2    = (const float*)d_in[10];
  const float* bg2    = (const float*)d_in[11];
  const float* rho    = (const float*)d_in[12];

  char* ws = (char*)d_ws;
  size_t off = 0;
  auto alloc = [&](size_t bytes)->char*{ char* p = ws + off; off += (bytes + 255) & ~(size_t)255; return p; };
  unsigned short* W1T      = (unsigned short*)alloc((size_t)1024*128*2);
  unsigned short* W2T      = (unsigned short*)alloc((size_t)128*128*2);
  unsigned short* Wg1T     = (unsigned short*)alloc((size_t)256*128*2);
  int*            rank     = (int*)alloc((size_t)EE*4);
  float2*         scp      = (float2*)alloc((size_t)EE*8);
  int*            bptr     = (int*)alloc((size_t)(NBUCK+1)*4);
  int*            counts   = (int*)alloc((size_t)NBUCK*4);
  int*            lexcl    = (int*)alloc((size_t)NBUCK*4);
  int*            bsum     = (int*)alloc((size_t)SCAN_BLKS*4);
  int*            bexcl    = (int*)alloc((size_t)SCAN_BLKS*4);
  unsigned short* h1       = (unsigned short*)alloc((size_t)NN*128*2);
  unsigned short* UH       = (unsigned short*)alloc((size_t)NN*256*2);
  float*          Vf       = (float*)alloc((size_t)NN*128*4);
  float*          hf_B     = (float*)alloc((size_t)NN*128*4);

  hipMemsetAsync(counts, 0, (size_t)NBUCK*4, stream);
  k_prep_all<<<704, 256, 0, stream>>>(W1, W2, Wg1, W1T, W2T, Wg1T);
  k_hist<<<EE/256, 256, 0, stream>>>(src, dst, counts, rank);
  k_scan1<<<SCAN_BLKS, 256, 0, stream>>>(counts, lexcl, bsum);
  k_scan_mid<<<1, 1024, 0, stream>>>(bsum, bexcl);
  k_scan3<<<SCAN_BLKS, 256, 0, stream>>>(lexcl, bexcl, bptr);
  k_fill<<<EE/256, 256, 0, stream>>>(src, dst, base_w, rho, bptr, rank, scp);

  k_enc1<<<1563, 256, 0, stream>>>(X, W1T, b1, h1);

  // layer 1
  k_uvA<<<782, 256, 0, stream>>>(h1, W2T, b2, Wg1T, bg1, UH, Vf);
  k_gate_agg<<<12500, 256, 0, stream>>>(UH, Vf, bptr, scp, Wg2, bg2, hf_B);
  // layer 2
  k_uvB<<<782, 256, 0, stream>>>(hf_B, Wg1T, bg1, UH, Vf);
  k_gate_agg<<<12500, 256, 0, stream>>>(UH, Vf, bptr, scp, Wg2, bg2, (float*)d_out);
}

// Round 14
// 498.671 us; speedup vs baseline: 1.0253x; 1.0227x over previous
//
#include <hip/hip_runtime.h>
#include <stdint.h>

#define NN 50000
#define CC 1024
#define HH 128
#define EE 1600000
#define EPSV 1e-8f
#define NSTRIPE 8
#define STRIPE_N 6250              // nodes per stripe (3.2MB of UH each)
#define NBUCK (NN*NSTRIPE)         // 400000 (dst,stripe) buckets
#define SCAN_BLKS 1563             // ceil(NBUCK/256)

typedef __attribute__((ext_vector_type(8))) short bf16x8;
typedef __attribute__((ext_vector_type(4))) float f32x4;
typedef __attribute__((ext_vector_type(2))) float f32x2;

__device__ __forceinline__ unsigned short f32_to_bf16(float f){
  union { float f; uint32_t u; } cv; cv.f = f;
  uint32_t u = cv.u;
  return (unsigned short)((u + 0x7FFFu + ((u >> 16) & 1u)) >> 16);
}
__device__ __forceinline__ float bf16lo_to_f32(uint32_t w){
  union { uint32_t u; float f; } cv; cv.u = w << 16; return cv.f;
}
__device__ __forceinline__ float bf16hi_to_f32(uint32_t w){
  union { uint32_t u; float f; } cv; cv.u = w & 0xFFFF0000u; return cv.f;
}

// DPP cross-lane add within a 16-lane row (xor1, xor2, ^7-in-8, mirror-16)
#define DPP_ADD(x, ctrl) ((x) + __int_as_float(__builtin_amdgcn_update_dpp(0, __float_as_int(x), (ctrl), 0xF, 0xF, true)))

// async global->LDS 16B DMA (lds dst wave-uniform base + lane*16; global src per-lane)
#define GLOAD_LDS16(g, l) __builtin_amdgcn_global_load_lds( \
    (const __attribute__((address_space(1))) uint32_t*)(g), \
    (__attribute__((address_space(3))) uint32_t*)(l), 16, 0, 0)

// ---------------- merged weight prep: W1T, W2T, Wg1T ----------------

__global__ __launch_bounds__(256) void k_prep_all(
    const float* __restrict__ W1, const float* __restrict__ W2,
    const float* __restrict__ Wg1,
    unsigned short* __restrict__ W1T, unsigned short* __restrict__ W2T,
    unsigned short* __restrict__ Wg1T){
  int idx = blockIdx.x*256 + threadIdx.x;
  if(idx < 131072){                                   // W1T[n][k] = W1[k][n]
    int n = idx >> 10, k = idx & 1023;
    W1T[idx] = f32_to_bf16(W1[k*128 + n]);
  } else if(idx < 131072 + 16384){                    // W2T[n][k] = W2[k][n]
    int i = idx - 131072;
    int n = i >> 7, k = i & 127;
    W2T[i] = f32_to_bf16(W2[k*128 + n]);
  } else if(idx < 131072 + 16384 + 32768){            // Wg1T[c][k]
    int i = idx - 131072 - 16384;
    int c = i >> 7, k = i & 127;
    int row = (c < 128) ? k : (128 + k);
    int col = (c < 128) ? c : (c - 128);
    Wg1T[i] = f32_to_bf16(Wg1[row*128 + col]);
  }
}

// ---------------- CSR build over (dst, src-stripe) buckets ----------------

__global__ __launch_bounds__(256) void k_hist(const int* __restrict__ src,
    const int* __restrict__ dst, int* __restrict__ counts,
    int* __restrict__ rank){
  int e = blockIdx.x*256 + threadIdx.x;
  if(e >= EE) return;
  int key = dst[e]*NSTRIPE + (int)((unsigned)src[e] / STRIPE_N);
  rank[e] = atomicAdd(&counts[key], 1);
}

__global__ __launch_bounds__(256) void k_scan1(const int* __restrict__ counts,
    int* __restrict__ lexcl, int* __restrict__ bsum){
  __shared__ int buf[256];
  const int t = threadIdx.x, i = blockIdx.x*256 + t;
  int v = (i < NBUCK) ? counts[i] : 0;
  buf[t] = v;
  __syncthreads();
  for(int off = 1; off < 256; off <<= 1){
    int add = (t >= off) ? buf[t-off] : 0;
    __syncthreads();
    buf[t] += add;
    __syncthreads();
  }
  if(i < NBUCK) lexcl[i] = buf[t] - v;
  if(t == 255) bsum[blockIdx.x] = buf[255];
}

// exclusive scan over the 1563 block sums (single 1024-thread block, 2 chunks)
__global__ __launch_bounds__(1024) void k_scan_mid(const int* __restrict__ bsum,
    int* __restrict__ bexcl){
  __shared__ int buf[1024];
  __shared__ int carry_s;
  const int t = threadIdx.x;
  if(t == 0) carry_s = 0;
  __syncthreads();
  for(int base = 0; base < SCAN_BLKS; base += 1024){
    int v = (base+t < SCAN_BLKS) ? bsum[base+t] : 0;
    buf[t] = v;
    __syncthreads();
    for(int off = 1; off < 1024; off <<= 1){
      int add = (t >= off) ? buf[t-off] : 0;
      __syncthreads();
      buf[t] += add;
      __syncthreads();
    }
    int carry = carry_s;
    if(base+t < SCAN_BLKS) bexcl[base+t] = carry + buf[t] - v;
    __syncthreads();
    if(t == 1023) carry_s = carry + buf[1023];
    __syncthreads();
  }
}

__global__ __launch_bounds__(256) void k_scan3(const int* __restrict__ lexcl,
    const int* __restrict__ bexcl, int* __restrict__ bptr){
  const int i = blockIdx.x*256 + threadIdx.x;
  if(i < NBUCK) bptr[i] = lexcl[i] + bexcl[blockIdx.x];
  if(i == 0) bptr[NBUCK] = EE;
}

// atomic-free fill: p = bptr[key] + rank; writes packed {c, src_bits}
__global__ __launch_bounds__(256) void k_fill(const int* __restrict__ src,
    const int* __restrict__ dst, const float* __restrict__ base_w,
    const float* __restrict__ rho_raw, const int* __restrict__ bptr,
    const int* __restrict__ rank, float2* __restrict__ scp){
  int e = blockIdx.x*256 + threadIdx.x;
  if(e >= EE) return;
  int s = src[e], d = dst[e];
  int key = d*NSTRIPE + (int)((unsigned)s / STRIPE_N);
  int p = bptr[key] + rank[e];
  float rs = 1.f/(1.f + __expf(-rho_raw[s]));
  float rd = 1.f/(1.f + __expf(-rho_raw[d]));
  scp[p] = make_float2(base_w[e]*rs*rd, __int_as_float(s));
}

// ---------------- encoder GEMM1: h1 = relu(X@W1 + b1) -> bf16 [N,128] ----------------
// 64-row M-tile (B-traffic 200MB, total VMEM 404MB) + counted vmcnt(4) 2-buffer
// pipeline (latency hidden across barriers). The r9/r12 2x2 completion:
// low-B-traffic geometry x non-draining sync.

__global__ __launch_bounds__(256) void k_enc1(
    const float* __restrict__ X, const unsigned short* __restrict__ W1T,
    const float* __restrict__ b1, unsigned short* __restrict__ h1)
{
  __shared__ __attribute__((aligned(16))) float          Af[2][64*32];    // 8KB each
  __shared__ __attribute__((aligned(16))) unsigned short Bf[2][128*32];   // 8KB each

  const int t = threadIdx.x, w = t >> 6, lane = t & 63;
  const int rowL = lane & 15, kq = lane >> 4;
  const int wm = w >> 1, wn = w & 1;
  const int row0 = blockIdx.x * 64;

  // A: wave w stages rows 16w..16w+15, two 1KB calls (8 rows each)
  const int a_rl0 = w*16 + (lane >> 3);
  const int a_cl  = lane & 7;
  int agr0 = row0 + a_rl0;     if(agr0 >= NN) agr0 = NN-1;
  int agr1 = row0 + a_rl0 + 8; if(agr1 >= NN) agr1 = NN-1;
  const float* a_src0 = X + (size_t)agr0*1024 + (a_cl ^ (a_rl0 & 7))*4;
  const float* a_src1 = X + (size_t)agr1*1024 + (a_cl ^ ((a_rl0+8) & 7))*4;
  // B: wave w stages rows 32w..32w+31, two calls of 16 rows
  const int b_rl0 = w*32 + (lane >> 2);
  const int b_cl  = lane & 3;
  const int bkey0 = (b_rl0 ^ (b_rl0 >> 2)) & 3;
  const int bkey1 = ((b_rl0+16) ^ ((b_rl0+16) >> 2)) & 3;
  const unsigned short* b_src0 = W1T + (size_t)b_rl0*1024 + (b_cl ^ bkey0)*8;
  const unsigned short* b_src1 = W1T + (size_t)(b_rl0+16)*1024 + (b_cl ^ bkey1)*8;

  #define STAGE(buf, k0)  do{                                              \
    GLOAD_LDS16(a_src0 + (k0), &Af[buf][(w*16    )*32]);                   \
    GLOAD_LDS16(a_src1 + (k0), &Af[buf][(w*16 + 8)*32]);                   \
    GLOAD_LDS16(b_src0 + (k0), &Bf[buf][(w*32     )*32]);                  \
    GLOAD_LDS16(b_src1 + (k0), &Bf[buf][(w*32 + 16)*32]);                  \
  }while(0)

  f32x4 acc[2][4] = {};
  const int arow0 = wm*32 + rowL;
  const int akey  = rowL & 7;
  const int bkeyR = (rowL ^ (rowL >> 2)) & 3;

  auto COMPUTE = [&](const float* afb, const unsigned short* bfb){
    bf16x8 af[2];
    #pragma unroll
    for(int mf = 0; mf < 2; mf++){
      const int ar = arow0 + mf*16;
      f32x4 x0 = *(const f32x4*)&afb[ar*32 + (((2*kq  ) ^ akey) << 2)];
      f32x4 x1 = *(const f32x4*)&afb[ar*32 + (((2*kq+1) ^ akey) << 2)];
      union { bf16x8 v; unsigned short s[8]; } pk;
      #pragma unroll
      for(int j = 0; j < 4; j++){ pk.s[j] = f32_to_bf16(x0[j]); pk.s[4+j] = f32_to_bf16(x1[j]); }
      af[mf] = pk.v;
    }
    bf16x8 bfr[4];
    #pragma unroll
    for(int nf = 0; nf < 4; nf++){
      const int br = wn*64 + nf*16 + rowL;
      bfr[nf] = *(const bf16x8*)&bfb[br*32 + ((kq ^ bkeyR) << 3)];
    }
    #pragma unroll
    for(int mf = 0; mf < 2; mf++)
      #pragma unroll
      for(int nf = 0; nf < 4; nf++)
        acc[mf][nf] = __builtin_amdgcn_mfma_f32_16x16x32_bf16(af[mf], bfr[nf], acc[mf][nf], 0, 0, 0);
  };

  // per step: STAGE(s+1) -> vmcnt(4) (step s's 4 calls done; s+1's stay in
  // flight) -> barrier -> sched_barrier -> compute s -> barrier.
  #define STEP(cbuf, sbuf, sk)  do{                                        \
    STAGE(sbuf, (sk)*32);                                                  \
    asm volatile("s_waitcnt vmcnt(4)" ::: "memory");                       \
    __builtin_amdgcn_s_barrier();                                          \
    __builtin_amdgcn_sched_barrier(0);                                     \
    COMPUTE(&Af[cbuf][0], &Bf[cbuf][0]);                                   \
    __builtin_amdgcn_s_barrier();                                          \
  }while(0)

  STAGE(0, 0);
  for(int tt = 0; tt < 30; tt += 2){
    STEP(0, 1, tt + 1);      // compute step tt (buf0), stage tt+1 -> buf1
    STEP(1, 0, tt + 2);      // compute step tt+1 (buf1), stage tt+2 -> buf0
  }
  STEP(0, 1, 31);            // compute step 30 (buf0), stage step 31 -> buf1
  asm volatile("s_waitcnt vmcnt(0)" ::: "memory");
  __builtin_amdgcn_s_barrier();
  __builtin_amdgcn_sched_barrier(0);
  COMPUTE(&Af[1][0], &Bf[1][0]);
  #undef STEP
  #undef STAGE

  // epilogue: bias + relu + bf16 store. C frag: row = kq*4+r, col = rowL.
  #pragma unroll
  for(int mf = 0; mf < 2; mf++){
    #pragma unroll
    for(int nf = 0; nf < 4; nf++){
      const int col = wn*64 + nf*16 + rowL;
      const float bv = b1[col];
      #pragma unroll
      for(int r = 0; r < 4; r++){
        const int gr = row0 + wm*32 + mf*16 + kq*4 + r;
        if(gr < NN) h1[(size_t)gr*128 + col] = f32_to_bf16(fmaxf(acc[mf][nf][r] + bv, 0.f));
      }
    }
  }
}

// ---------------- shared UV phase: [u|v] = h @ Wg1 from swizzled LDS (h AND Wg1T) ----------------

__device__ __forceinline__ void uv_phase2(
    const unsigned short* hs, const unsigned short* wgl, int row0, int wave, int lane,
    const float* __restrict__ bg1,
    unsigned short* __restrict__ UH, float* __restrict__ Vf)
{
  const int rowL = lane & 15, kq = lane >> 4;
  const int r = wave*16 + rowL;
  f32x4 acc[16] = {};
  #pragma unroll
  for(int ks = 0; ks < 4; ks++){
    const int kc = ks*4 + kq;
    bf16x8 a = *(const bf16x8*)&hs[r*128 + ((kc ^ (r & 15)) << 3)];
    #pragma unroll
    for(int nt = 0; nt < 16; nt++){
      bf16x8 b = *(const bf16x8*)&wgl[(nt*16 + rowL)*128 + ((kc ^ rowL) << 3)];
      acc[nt] = __builtin_amdgcn_mfma_f32_16x16x32_bf16(a, b, acc[nt], 0, 0, 0);
    }
  }
  #pragma unroll
  for(int nt = 0; nt < 16; nt++){
    const int col = nt*16 + rowL;
    #pragma unroll
    for(int rr = 0; rr < 4; rr++){
      const int gr = row0 + wave*16 + kq*4 + rr;
      if(gr < NN){
        if(col < 128) UH[(size_t)gr*256 + col] = f32_to_bf16(acc[nt][rr]);
        else          Vf[(size_t)gr*128 + col - 128] = acc[nt][rr] + bg1[col - 128];
      }
    }
  }
}

// ---------------- k_uvA: h = relu(h1@W2T + b2); writes UH=[u|h] bf16, Vf=v+bg1 ----------------

__global__ __launch_bounds__(256) void k_uvA(
    const unsigned short* __restrict__ h1, const unsigned short* __restrict__ W2T,
    const float* __restrict__ b2, const unsigned short* __restrict__ Wg1T,
    const float* __restrict__ bg1, unsigned short* __restrict__ UH,
    float* __restrict__ Vf)
{
  __shared__ __attribute__((aligned(16))) unsigned short hs[64*128];
  __shared__ __attribute__((aligned(16))) unsigned short wgl[256*128];
  const int t = threadIdx.x, wave = t >> 6, lane = t & 63;
  const int rowL = lane & 15, kq = lane >> 4;
  const int row0 = blockIdx.x*64;

  bf16x8 wreg[16];
  #pragma unroll
  for(int i = 0; i < 16; i++)
    wreg[i] = *(const bf16x8*)(Wg1T + (i*256 + t)*8);

  int ar = row0 + wave*16 + rowL; if(ar >= NN) ar = NN-1;
  f32x4 acc[8] = {};
  #pragma unroll
  for(int ks = 0; ks < 4; ks++){
    bf16x8 a = *(const bf16x8*)(h1 + (size_t)ar*128 + ks*32 + kq*8);
    #pragma unroll
    for(int nt = 0; nt < 8; nt++){
      bf16x8 b = *(const bf16x8*)(W2T + (nt*16 + rowL)*128 + ks*32 + kq*8);
      acc[nt] = __builtin_amdgcn_mfma_f32_16x16x32_bf16(a, b, acc[nt], 0, 0, 0);
    }
  }
  #pragma unroll
  for(int nt = 0; nt < 8; nt++){
    const int col = nt*16 + rowL;
    const float bv = b2[col];
    #pragma unroll
    for(int r = 0; r < 4; r++){
      const int rw = wave*16 + kq*4 + r;
      const unsigned short hv = f32_to_bf16(fmaxf(acc[nt][r] + bv, 0.f));
      hs[rw*128 + (((col >> 3) ^ (rw & 15)) << 3) + (col & 7)] = hv;
    }
  }
  #pragma unroll
  for(int i = 0; i < 16; i++){
    const int idx = i*256 + t, row = idx >> 4, c = idx & 15;
    *(bf16x8*)&wgl[row*128 + ((c ^ (row & 15)) << 3)] = wreg[i];
  }
  __syncthreads();
  {
    const int r = t >> 2, gr = row0 + r;
    if(gr < NN){
      #pragma unroll
      for(int j8 = 0; j8 < 4; j8++){
        const int chunk = (t & 3)*4 + j8;
        bf16x8 v = *(const bf16x8*)&hs[r*128 + ((chunk ^ (r & 15)) << 3)];
        *(bf16x8*)&UH[(size_t)gr*256 + 128 + chunk*8] = v;
      }
    }
  }
  uv_phase2(hs, wgl, row0, wave, lane, bg1, UH, Vf);
}

// ---------------- k_uvB: input h f32 (agg output); writes UH=[u|h] bf16, Vf=v+bg1 ----------------

__global__ __launch_bounds__(256) void k_uvB(
    const float* __restrict__ hf, const unsigned short* __restrict__ Wg1T,
    const float* __restrict__ bg1, unsigned short* __restrict__ UH,
    float* __restrict__ Vf)
{
  __shared__ __attribute__((aligned(16))) unsigned short hs[64*128];
  __shared__ __attribute__((aligned(16))) unsigned short wgl[256*128];
  const int t = threadIdx.x, wave = t >> 6, lane = t & 63;
  const int row0 = blockIdx.x*64;

  bf16x8 wreg[16];
  #pragma unroll
  for(int i = 0; i < 16; i++)
    wreg[i] = *(const bf16x8*)(Wg1T + (i*256 + t)*8);

  {
    const int r = t >> 2, gr0 = row0 + r;
    const int gr = (gr0 < NN) ? gr0 : NN-1;
    const float* p = hf + (size_t)gr*128 + (t & 3)*32;
    #pragma unroll
    for(int j8 = 0; j8 < 4; j8++){
      f32x4 v0 = *(const f32x4*)(p + j8*8);
      f32x4 v1 = *(const f32x4*)(p + j8*8 + 4);
      union { bf16x8 v; unsigned short s[8]; } pk;
      #pragma unroll
      for(int j = 0; j < 4; j++){ pk.s[j] = f32_to_bf16(v0[j]); pk.s[4+j] = f32_to_bf16(v1[j]); }
      const int chunk = (t & 3)*4 + j8;
      *(bf16x8*)&hs[r*128 + ((chunk ^ (r & 15)) << 3)] = pk.v;
      if(gr0 < NN) *(bf16x8*)&UH[(size_t)gr0*256 + 128 + chunk*8] = pk.v;
    }
  }
  #pragma unroll
  for(int i = 0; i < 16; i++){
    const int idx = i*256 + t, row = idx >> 4, c = idx & 15;
    *(bf16x8*)&wgl[row*128 + ((c ^ (row & 15)) << 3)] = wreg[i];
  }
  __syncthreads();
  uv_phase2(hs, wgl, row0, wave, lane & 63, bg1, UH, Vf);
}

// ---------------- fused gate + aggregation, stripe-sorted CSR, one wave per dst ----------------

__global__ __launch_bounds__(256) void k_gate_agg(
    const unsigned short* __restrict__ UH, const float* __restrict__ Vf,
    const int* __restrict__ bptr, const float2* __restrict__ scp,
    const float* __restrict__ Wg2, const float* __restrict__ bg2p,
    float* __restrict__ out_f32)
{
  __shared__ float2 ws_s[4][64];
  const int wv = threadIdx.x >> 6, lane = threadIdx.x & 63;
  const int gw = blockIdx.x*4 + wv;
  if(gw >= NN) return;
  const int eq = lane >> 4, li = lane & 15;

  f32x4 va = *(const f32x4*)(Vf + (size_t)gw*128 + li*8);
  f32x4 vb = *(const f32x4*)(Vf + (size_t)gw*128 + li*8 + 4);
  f32x4 wa = *(const f32x4*)(Wg2 + li*8);
  f32x4 wb = *(const f32x4*)(Wg2 + li*8 + 4);
  const float vch[8]  = {va[0],va[1],va[2],va[3],vb[0],vb[1],vb[2],vb[3]};
  const float w2ch[8] = {wa[0],wa[1],wa[2],wa[3],wb[0],wb[1],wb[2],wb[3]};
  const float bg2v = bg2p[0];

  const int beg = bptr[gw*NSTRIPE], end = bptr[gw*NSTRIPE + NSTRIPE];
  float a0 = 0.f, a1 = 0.f, wsum = 0.f;

  for(int base = beg; base < end; base += 64){
    const int nb = min(64, end - base);

    float2 sc_c0, sc_c1; bf16x8 u_c0, u_c1;
    {
      const int i0 = (eq     < nb) ? eq     : 0;
      const int i1 = (4 + eq < nb) ? 4 + eq : 0;
      sc_c0 = scp[base + i0]; sc_c1 = scp[base + i1];
      u_c0 = *(const bf16x8*)&UH[(uint32_t)__float_as_int(sc_c0.y)*256u + li*8];
      u_c1 = *(const bf16x8*)&UH[(uint32_t)__float_as_int(sc_c1.y)*256u + li*8];
    }
    for(int q = 0; q < nb; q += 8){
      float2 sc_n0 = sc_c0, sc_n1 = sc_c1; bf16x8 u_n0 = u_c0, u_n1 = u_c1;
      if(q + 8 < nb){
        const int i0 = (q + 8  + eq < nb) ? q + 8  + eq : 0;
        const int i1 = (q + 12 + eq < nb) ? q + 12 + eq : 0;
        sc_n0 = scp[base + i0]; sc_n1 = scp[base + i1];
        u_n0 = *(const bf16x8*)&UH[(uint32_t)__float_as_int(sc_n0.y)*256u + li*8];
        u_n1 = *(const bf16x8*)&UH[(uint32_t)__float_as_int(sc_n1.y)*256u + li*8];
      }
      { // edge A: idx = q + eq
        union { bf16x8 v; uint32_t u32[4]; } uu; uu.v = u_c0;
        float tacc = 0.f;
        #pragma unroll
        for(int p = 0; p < 4; p++){
          const uint32_t w2b = uu.u32[p];
          tacc += fmaxf(bf16lo_to_f32(w2b) + vch[2*p],   0.f) * w2ch[2*p];
          tacc += fmaxf(bf16hi_to_f32(w2b) + vch[2*p+1], 0.f) * w2ch[2*p+1];
        }
        tacc = DPP_ADD(tacc, 0xB1);
        tacc = DPP_ADD(tacc, 0x4E);
        tacc = DPP_ADD(tacc, 0x141);
        tacc = DPP_ADD(tacc, 0x140);
        const float g = 1.f/(1.f + __expf(-(tacc + bg2v)));
        const int idx = q + eq;
        if(li == 0 && idx < nb) ws_s[wv][idx] = make_float2(sc_c0.x*g, sc_c0.y);
      }
      { // edge B: idx = q + 4 + eq
        union { bf16x8 v; uint32_t u32[4]; } uu; uu.v = u_c1;
        float tacc = 0.f;
        #pragma unroll
        for(int p = 0; p < 4; p++){
          const uint32_t w2b = uu.u32[p];
          tacc += fmaxf(bf16lo_to_f32(w2b) + vch[2*p],   0.f) * w2ch[2*p];
          tacc += fmaxf(bf16hi_to_f32(w2b) + vch[2*p+1], 0.f) * w2ch[2*p+1];
        }
        tacc = DPP_ADD(tacc, 0xB1);
        tacc = DPP_ADD(tacc, 0x4E);
        tacc = DPP_ADD(tacc, 0x141);
        tacc = DPP_ADD(tacc, 0x140);
        const float g = 1.f/(1.f + __expf(-(tacc + bg2v)));
        const int idx = q + 4 + eq;
        if(li == 0 && idx < nb) ws_s[wv][idx] = make_float2(sc_c1.x*g, sc_c1.y);
      }
      sc_c0 = sc_n0; sc_c1 = sc_n1; u_c0 = u_n0; u_c1 = u_n1;
    }

    #pragma unroll 8
    for(int j = 0; j < nb; j++){
      const float2 p = ws_s[wv][j];
      const float w  = p.x;
      const uint32_t s = (uint32_t)__float_as_int(p.y);
      const uint32_t hw = *(const uint32_t*)&UH[s*256u + 128u + lane*2];
      a0 += w*bf16lo_to_f32(hw);
      a1 += w*bf16hi_to_f32(hw);
      wsum += w;
    }
  }
  const float inv = 1.f/(wsum + EPSV);
  const size_t o = (size_t)gw*128 + lane*2;
  *(f32x2*)&out_f32[o] = (f32x2){a0*inv, a1*inv};
}

// ---------------- launch ----------------

extern "C" void kernel_launch(void* const* d_in, const int* in_sizes, int n_in,
                              void* d_out, int out_size, void* d_ws, size_t ws_size,
                              hipStream_t stream) {
  (void)in_sizes; (void)n_in; (void)out_size; (void)ws_size;
  const float* X      = (const float*)d_in[0];
  const int*   src    = (const int*)d_in[1];
  const int*   dst    = (const int*)d_in[2];
  const float* base_w = (const float*)d_in[3];
  const float* W1     = (const float*)d_in[4];
  const float* b1     = (const float*)d_in[5];
  const float* W2     = (const float*)d_in[6];
  const float* b2     = (const float*)d_in[7];
  const float* Wg1    = (const float*)d_in[8];
  const float* bg1    = (const float*)d_in[9];
  const float* Wg2    = (const float*)d_in[10];
  const float* bg2    = (const float*)d_in[11];
  const float* rho    = (const float*)d_in[12];

  char* ws = (char*)d_ws;
  size_t off = 0;
  auto alloc = [&](size_t bytes)->char*{ char* p = ws + off; off += (bytes + 255) & ~(size_t)255; return p; };
  unsigned short* W1T      = (unsigned short*)alloc((size_t)1024*128*2);
  unsigned short* W2T      = (unsigned short*)alloc((size_t)128*128*2);
  unsigned short* Wg1T     = (unsigned short*)alloc((size_t)256*128*2);
  int*            rank     = (int*)alloc((size_t)EE*4);
  float2*         scp      = (float2*)alloc((size_t)EE*8);
  int*            bptr     = (int*)alloc((size_t)(NBUCK+1)*4);
  int*            counts   = (int*)alloc((size_t)NBUCK*4);
  int*            lexcl    = (int*)alloc((size_t)NBUCK*4);
  int*            bsum     = (int*)alloc((size_t)SCAN_BLKS*4);
  int*            bexcl    = (int*)alloc((size_t)SCAN_BLKS*4);
  unsigned short* h1       = (unsigned short*)alloc((size_t)NN*128*2);
  unsigned short* UH       = (unsigned short*)alloc((size_t)NN*256*2);
  float*          Vf       = (float*)alloc((size_t)NN*128*4);
  float*          hf_B     = (float*)alloc((size_t)NN*128*4);

  hipMemsetAsync(counts, 0, (size_t)NBUCK*4, stream);
  k_prep_all<<<704, 256, 0, stream>>>(W1, W2, Wg1, W1T, W2T, Wg1T);
  k_hist<<<EE/256, 256, 0, stream>>>(src, dst, counts, rank);
  k_scan1<<<SCAN_BLKS, 256, 0, stream>>>(counts, lexcl, bsum);
  k_scan_mid<<<1, 1024, 0, stream>>>(bsum, bexcl);
  k_scan3<<<SCAN_BLKS, 256, 0, stream>>>(lexcl, bexcl, bptr);
  k_fill<<<EE/256, 256, 0, stream>>>(src, dst, base_w, rho, bptr, rank, scp);

  k_enc1<<<782, 256, 0, stream>>>(X, W1T, b1, h1);

  // layer 1
  k_uvA<<<782, 256, 0, stream>>>(h1, W2T, b2, Wg1T, bg1, UH, Vf);
  k_gate_agg<<<12500, 256, 0, stream>>>(UH, Vf, bptr, scp, Wg2, bg2, hf_B);
  // layer 2
  k_uvB<<<782, 256, 0, stream>>>(hf_B, Wg1T, bg1, UH, Vf);
  k_gate_agg<<<12500, 256, 0, stream>>>(UH, Vf, bptr, scp, Wg2, bg2, (float*)d_out);
}

// Round 15
// 443.419 us; speedup vs baseline: 1.1530x; 1.1246x over previous
//
#include <hip/hip_runtime.h>
#include <stdint.h>

#define NN 50000
#define CC 1024
#define HH 128
#define EE 1600000
#define EPSV 1e-8f
#define NSTRIPE 8
#define STRIPE_N 6250              // nodes per stripe
#define NBUCK (NN*NSTRIPE)         // 400000 (dst,stripe) buckets
#define SCAN_BLKS 1563             // ceil(NBUCK/256)
#define ENC_BLKS 782               // encoder tile blocks (64 rows each)
#define UV_BLKS 782
#define EDGE_BLKS (EE/256)         // 6250

typedef __attribute__((ext_vector_type(8))) short bf16x8;
typedef __attribute__((ext_vector_type(4))) float f32x4;
typedef __attribute__((ext_vector_type(2))) float f32x2;

__device__ __forceinline__ unsigned short f32_to_bf16(float f){
  union { float f; uint32_t u; } cv; cv.f = f;
  uint32_t u = cv.u;
  return (unsigned short)((u + 0x7FFFu + ((u >> 16) & 1u)) >> 16);
}
__device__ __forceinline__ float bf16lo_to_f32(uint32_t w){
  union { uint32_t u; float f; } cv; cv.u = w << 16; return cv.f;
}
__device__ __forceinline__ float bf16hi_to_f32(uint32_t w){
  union { uint32_t u; float f; } cv; cv.u = w & 0xFFFF0000u; return cv.f;
}

// DPP cross-lane add within a 16-lane row (xor1, xor2, ^7-in-8, mirror-16)
#define DPP_ADD(x, ctrl) ((x) + __int_as_float(__builtin_amdgcn_update_dpp(0, __float_as_int(x), (ctrl), 0xF, 0xF, true)))

// async global->LDS 16B DMA
#define GLOAD_LDS16(g, l) __builtin_amdgcn_global_load_lds( \
    (const __attribute__((address_space(1))) uint32_t*)(g), \
    (__attribute__((address_space(3))) uint32_t*)(l), 16, 0, 0)

// ---------------- merged weight prep: W1T, W2T, Wg1T ----------------

__global__ __launch_bounds__(256) void k_prep_all(
    const float* __restrict__ W1, const float* __restrict__ W2,
    const float* __restrict__ Wg1,
    unsigned short* __restrict__ W1T, unsigned short* __restrict__ W2T,
    unsigned short* __restrict__ Wg1T){
  int idx = blockIdx.x*256 + threadIdx.x;
  if(idx < 131072){                                   // W1T[n][k] = W1[k][n]
    int n = idx >> 10, k = idx & 1023;
    W1T[idx] = f32_to_bf16(W1[k*128 + n]);
  } else if(idx < 131072 + 16384){                    // W2T[n][k] = W2[k][n]
    int i = idx - 131072;
    int n = i >> 7, k = i & 127;
    W2T[i] = f32_to_bf16(W2[k*128 + n]);
  } else if(idx < 131072 + 16384 + 32768){            // Wg1T[c][k]
    int i = idx - 131072 - 16384;
    int c = i >> 7, k = i & 127;
    int row = (c < 128) ? k : (128 + k);
    int col = (c < 128) ? c : (c - 128);
    Wg1T[i] = f32_to_bf16(Wg1[row*128 + col]);
  }
}

// ---------------- FUSED: encoder GEMM1 (blocks 0..781) + hist (blocks 782+) ----------------
// enc1: 64-row M-tile, 2-buffer global_load_lds pipeline, counted vmcnt(4).
// hist: rank[e] = atomicAdd(counts[dst*8+stripe(src)], 1). Independent work
// backfills CU issue slots under enc1's memory stalls.

__global__ __launch_bounds__(256) void k_enc1_hist(
    const float* __restrict__ X, const unsigned short* __restrict__ W1T,
    const float* __restrict__ b1, unsigned short* __restrict__ h1,
    const int* __restrict__ src, const int* __restrict__ dst,
    int* __restrict__ counts, int* __restrict__ rank)
{
  __shared__ __attribute__((aligned(16))) float          Af[2][64*32];    // 8KB each
  __shared__ __attribute__((aligned(16))) unsigned short Bf[2][128*32];   // 8KB each

  if(blockIdx.x >= ENC_BLKS){
    int e = (blockIdx.x - ENC_BLKS)*256 + threadIdx.x;
    if(e < EE){
      int key = dst[e]*NSTRIPE + (int)((unsigned)src[e] / STRIPE_N);
      rank[e] = atomicAdd(&counts[key], 1);
    }
    return;
  }

  const int t = threadIdx.x, w = t >> 6, lane = t & 63;
  const int rowL = lane & 15, kq = lane >> 4;
  const int wm = w >> 1, wn = w & 1;
  const int row0 = blockIdx.x * 64;

  const int a_rl0 = w*16 + (lane >> 3);
  const int a_cl  = lane & 7;
  int agr0 = row0 + a_rl0;     if(agr0 >= NN) agr0 = NN-1;
  int agr1 = row0 + a_rl0 + 8; if(agr1 >= NN) agr1 = NN-1;
  const float* a_src0 = X + (size_t)agr0*1024 + (a_cl ^ (a_rl0 & 7))*4;
  const float* a_src1 = X + (size_t)agr1*1024 + (a_cl ^ ((a_rl0+8) & 7))*4;
  const int b_rl0 = w*32 + (lane >> 2);
  const int b_cl  = lane & 3;
  const int bkey0 = (b_rl0 ^ (b_rl0 >> 2)) & 3;
  const int bkey1 = ((b_rl0+16) ^ ((b_rl0+16) >> 2)) & 3;
  const unsigned short* b_src0 = W1T + (size_t)b_rl0*1024 + (b_cl ^ bkey0)*8;
  const unsigned short* b_src1 = W1T + (size_t)(b_rl0+16)*1024 + (b_cl ^ bkey1)*8;

  #define STAGE(buf, k0)  do{                                              \
    GLOAD_LDS16(a_src0 + (k0), &Af[buf][(w*16    )*32]);                   \
    GLOAD_LDS16(a_src1 + (k0), &Af[buf][(w*16 + 8)*32]);                   \
    GLOAD_LDS16(b_src0 + (k0), &Bf[buf][(w*32     )*32]);                  \
    GLOAD_LDS16(b_src1 + (k0), &Bf[buf][(w*32 + 16)*32]);                  \
  }while(0)

  f32x4 acc[2][4] = {};
  const int arow0 = wm*32 + rowL;
  const int akey  = rowL & 7;
  const int bkeyR = (rowL ^ (rowL >> 2)) & 3;

  auto COMPUTE = [&](const float* afb, const unsigned short* bfb){
    bf16x8 af[2];
    #pragma unroll
    for(int mf = 0; mf < 2; mf++){
      const int ar = arow0 + mf*16;
      f32x4 x0 = *(const f32x4*)&afb[ar*32 + (((2*kq  ) ^ akey) << 2)];
      f32x4 x1 = *(const f32x4*)&afb[ar*32 + (((2*kq+1) ^ akey) << 2)];
      union { bf16x8 v; unsigned short s[8]; } pk;
      #pragma unroll
      for(int j = 0; j < 4; j++){ pk.s[j] = f32_to_bf16(x0[j]); pk.s[4+j] = f32_to_bf16(x1[j]); }
      af[mf] = pk.v;
    }
    bf16x8 bfr[4];
    #pragma unroll
    for(int nf = 0; nf < 4; nf++){
      const int br = wn*64 + nf*16 + rowL;
      bfr[nf] = *(const bf16x8*)&bfb[br*32 + ((kq ^ bkeyR) << 3)];
    }
    #pragma unroll
    for(int mf = 0; mf < 2; mf++)
      #pragma unroll
      for(int nf = 0; nf < 4; nf++)
        acc[mf][nf] = __builtin_amdgcn_mfma_f32_16x16x32_bf16(af[mf], bfr[nf], acc[mf][nf], 0, 0, 0);
  };

  #define STEP(cbuf, sbuf, sk)  do{                                        \
    STAGE(sbuf, (sk)*32);                                                  \
    asm volatile("s_waitcnt vmcnt(4)" ::: "memory");                       \
    __builtin_amdgcn_s_barrier();                                          \
    __builtin_amdgcn_sched_barrier(0);                                     \
    COMPUTE(&Af[cbuf][0], &Bf[cbuf][0]);                                   \
    __builtin_amdgcn_s_barrier();                                          \
  }while(0)

  STAGE(0, 0);
  for(int tt = 0; tt < 30; tt += 2){
    STEP(0, 1, tt + 1);
    STEP(1, 0, tt + 2);
  }
  STEP(0, 1, 31);
  asm volatile("s_waitcnt vmcnt(0)" ::: "memory");
  __builtin_amdgcn_s_barrier();
  __builtin_amdgcn_sched_barrier(0);
  COMPUTE(&Af[1][0], &Bf[1][0]);
  #undef STEP
  #undef STAGE

  #pragma unroll
  for(int mf = 0; mf < 2; mf++){
    #pragma unroll
    for(int nf = 0; nf < 4; nf++){
      const int col = wn*64 + nf*16 + rowL;
      const float bv = b1[col];
      #pragma unroll
      for(int r = 0; r < 4; r++){
        const int gr = row0 + wm*32 + mf*16 + kq*4 + r;
        if(gr < NN) h1[(size_t)gr*128 + col] = f32_to_bf16(fmaxf(acc[mf][nf][r] + bv, 0.f));
      }
    }
  }
}

// ---------------- scans (unchanged) ----------------

__global__ __launch_bounds__(256) void k_scan1(const int* __restrict__ counts,
    int* __restrict__ lexcl, int* __restrict__ bsum){
  __shared__ int buf[256];
  const int t = threadIdx.x, i = blockIdx.x*256 + t;
  int v = (i < NBUCK) ? counts[i] : 0;
  buf[t] = v;
  __syncthreads();
  for(int off = 1; off < 256; off <<= 1){
    int add = (t >= off) ? buf[t-off] : 0;
    __syncthreads();
    buf[t] += add;
    __syncthreads();
  }
  if(i < NBUCK) lexcl[i] = buf[t] - v;
  if(t == 255) bsum[blockIdx.x] = buf[255];
}

__global__ __launch_bounds__(1024) void k_scan_mid(const int* __restrict__ bsum,
    int* __restrict__ bexcl){
  __shared__ int buf[1024];
  __shared__ int carry_s;
  const int t = threadIdx.x;
  if(t == 0) carry_s = 0;
  __syncthreads();
  for(int base = 0; base < SCAN_BLKS; base += 1024){
    int v = (base+t < SCAN_BLKS) ? bsum[base+t] : 0;
    buf[t] = v;
    __syncthreads();
    for(int off = 1; off < 1024; off <<= 1){
      int add = (t >= off) ? buf[t-off] : 0;
      __syncthreads();
      buf[t] += add;
      __syncthreads();
    }
    int carry = carry_s;
    if(base+t < SCAN_BLKS) bexcl[base+t] = carry + buf[t] - v;
    __syncthreads();
    if(t == 1023) carry_s = carry + buf[1023];
    __syncthreads();
  }
}

__global__ __launch_bounds__(256) void k_scan3(const int* __restrict__ lexcl,
    const int* __restrict__ bexcl, int* __restrict__ bptr){
  const int i = blockIdx.x*256 + threadIdx.x;
  if(i < NBUCK) bptr[i] = lexcl[i] + bexcl[blockIdx.x];
  if(i == 0) bptr[NBUCK] = EE;
}

// ---------------- shared UV phase ----------------

__device__ __forceinline__ void uv_phase2(
    const unsigned short* hs, const unsigned short* wgl, int row0, int wave, int lane,
    const float* __restrict__ bg1,
    unsigned short* __restrict__ UH, float* __restrict__ Vf)
{
  const int rowL = lane & 15, kq = lane >> 4;
  const int r = wave*16 + rowL;
  f32x4 acc[16] = {};
  #pragma unroll
  for(int ks = 0; ks < 4; ks++){
    const int kc = ks*4 + kq;
    bf16x8 a = *(const bf16x8*)&hs[r*128 + ((kc ^ (r & 15)) << 3)];
    #pragma unroll
    for(int nt = 0; nt < 16; nt++){
      bf16x8 b = *(const bf16x8*)&wgl[(nt*16 + rowL)*128 + ((kc ^ rowL) << 3)];
      acc[nt] = __builtin_amdgcn_mfma_f32_16x16x32_bf16(a, b, acc[nt], 0, 0, 0);
    }
  }
  #pragma unroll
  for(int nt = 0; nt < 16; nt++){
    const int col = nt*16 + rowL;
    #pragma unroll
    for(int rr = 0; rr < 4; rr++){
      const int gr = row0 + wave*16 + kq*4 + rr;
      if(gr < NN){
        if(col < 128) UH[(size_t)gr*256 + col] = f32_to_bf16(acc[nt][rr]);
        else          Vf[(size_t)gr*128 + col - 128] = acc[nt][rr] + bg1[col - 128];
      }
    }
  }
}

// ---------------- FUSED: k_uvA (blocks 0..781) + fill (blocks 782+) ----------------
// fill: p = bptr[key] + rank[e]; scp[p] = {c, src}. Memory-bound scatter hides
// under uvA's MFMA-dense phase.

__global__ __launch_bounds__(256) void k_uvA_fill(
    const unsigned short* __restrict__ h1, const unsigned short* __restrict__ W2T,
    const float* __restrict__ b2, const unsigned short* __restrict__ Wg1T,
    const float* __restrict__ bg1, unsigned short* __restrict__ UH,
    float* __restrict__ Vf,
    const int* __restrict__ src, const int* __restrict__ dst,
    const float* __restrict__ base_w, const float* __restrict__ rho_raw,
    const int* __restrict__ bptr, const int* __restrict__ rank,
    float2* __restrict__ scp)
{
  __shared__ __attribute__((aligned(16))) unsigned short hs[64*128];
  __shared__ __attribute__((aligned(16))) unsigned short wgl[256*128];

  if(blockIdx.x >= UV_BLKS){
    int e = (blockIdx.x - UV_BLKS)*256 + threadIdx.x;
    if(e < EE){
      int s = src[e], d = dst[e];
      int key = d*NSTRIPE + (int)((unsigned)s / STRIPE_N);
      int p = bptr[key] + rank[e];
      float rs = 1.f/(1.f + __expf(-rho_raw[s]));
      float rd = 1.f/(1.f + __expf(-rho_raw[d]));
      scp[p] = make_float2(base_w[e]*rs*rd, __int_as_float(s));
    }
    return;
  }

  const int t = threadIdx.x, wave = t >> 6, lane = t & 63;
  const int rowL = lane & 15, kq = lane >> 4;
  const int row0 = blockIdx.x*64;

  bf16x8 wreg[16];
  #pragma unroll
  for(int i = 0; i < 16; i++)
    wreg[i] = *(const bf16x8*)(Wg1T + (i*256 + t)*8);

  int ar = row0 + wave*16 + rowL; if(ar >= NN) ar = NN-1;
  f32x4 acc[8] = {};
  #pragma unroll
  for(int ks = 0; ks < 4; ks++){
    bf16x8 a = *(const bf16x8*)(h1 + (size_t)ar*128 + ks*32 + kq*8);
    #pragma unroll
    for(int nt = 0; nt < 8; nt++){
      bf16x8 b = *(const bf16x8*)(W2T + (nt*16 + rowL)*128 + ks*32 + kq*8);
      acc[nt] = __builtin_amdgcn_mfma_f32_16x16x32_bf16(a, b, acc[nt], 0, 0, 0);
    }
  }
  #pragma unroll
  for(int nt = 0; nt < 8; nt++){
    const int col = nt*16 + rowL;
    const float bv = b2[col];
    #pragma unroll
    for(int r = 0; r < 4; r++){
      const int rw = wave*16 + kq*4 + r;
      const unsigned short hv = f32_to_bf16(fmaxf(acc[nt][r] + bv, 0.f));
      hs[rw*128 + (((col >> 3) ^ (rw & 15)) << 3) + (col & 7)] = hv;
    }
  }
  #pragma unroll
  for(int i = 0; i < 16; i++){
    const int idx = i*256 + t, row = idx >> 4, c = idx & 15;
    *(bf16x8*)&wgl[row*128 + ((c ^ (row & 15)) << 3)] = wreg[i];
  }
  __syncthreads();
  {
    const int r = t >> 2, gr = row0 + r;
    if(gr < NN){
      #pragma unroll
      for(int j8 = 0; j8 < 4; j8++){
        const int chunk = (t & 3)*4 + j8;
        bf16x8 v = *(const bf16x8*)&hs[r*128 + ((chunk ^ (r & 15)) << 3)];
        *(bf16x8*)&UH[(size_t)gr*256 + 128 + chunk*8] = v;
      }
    }
  }
  uv_phase2(hs, wgl, row0, wave, lane, bg1, UH, Vf);
}

// ---------------- k_uvB: input h f32 (agg output) ----------------

__global__ __launch_bounds__(256) void k_uvB(
    const float* __restrict__ hf, const unsigned short* __restrict__ Wg1T,
    const float* __restrict__ bg1, unsigned short* __restrict__ UH,
    float* __restrict__ Vf)
{
  __shared__ __attribute__((aligned(16))) unsigned short hs[64*128];
  __shared__ __attribute__((aligned(16))) unsigned short wgl[256*128];
  const int t = threadIdx.x, wave = t >> 6, lane = t & 63;
  const int row0 = blockIdx.x*64;

  bf16x8 wreg[16];
  #pragma unroll
  for(int i = 0; i < 16; i++)
    wreg[i] = *(const bf16x8*)(Wg1T + (i*256 + t)*8);

  {
    const int r = t >> 2, gr0 = row0 + r;
    const int gr = (gr0 < NN) ? gr0 : NN-1;
    const float* p = hf + (size_t)gr*128 + (t & 3)*32;
    #pragma unroll
    for(int j8 = 0; j8 < 4; j8++){
      f32x4 v0 = *(const f32x4*)(p + j8*8);
      f32x4 v1 = *(const f32x4*)(p + j8*8 + 4);
      union { bf16x8 v; unsigned short s[8]; } pk;
      #pragma unroll
      for(int j = 0; j < 4; j++){ pk.s[j] = f32_to_bf16(v0[j]); pk.s[4+j] = f32_to_bf16(v1[j]); }
      const int chunk = (t & 3)*4 + j8;
      *(bf16x8*)&hs[r*128 + ((chunk ^ (r & 15)) << 3)] = pk.v;
      if(gr0 < NN) *(bf16x8*)&UH[(size_t)gr0*256 + 128 + chunk*8] = pk.v;
    }
  }
  #pragma unroll
  for(int i = 0; i < 16; i++){
    const int idx = i*256 + t, row = idx >> 4, c = idx & 15;
    *(bf16x8*)&wgl[row*128 + ((c ^ (row & 15)) << 3)] = wreg[i];
  }
  __syncthreads();
  uv_phase2(hs, wgl, row0, wave, lane & 63, bg1, UH, Vf);
}

// ---------------- fused gate + aggregation, stripe-sorted CSR, one wave per dst ----------------

__global__ __launch_bounds__(256) void k_gate_agg(
    const unsigned short* __restrict__ UH, const float* __restrict__ Vf,
    const int* __restrict__ bptr, const float2* __restrict__ scp,
    const float* __restrict__ Wg2, const float* __restrict__ bg2p,
    float* __restrict__ out_f32)
{
  __shared__ float2 ws_s[4][64];
  const int wv = threadIdx.x >> 6, lane = threadIdx.x & 63;
  const int gw = blockIdx.x*4 + wv;
  if(gw >= NN) return;
  const int eq = lane >> 4, li = lane & 15;

  f32x4 va = *(const f32x4*)(Vf + (size_t)gw*128 + li*8);
  f32x4 vb = *(const f32x4*)(Vf + (size_t)gw*128 + li*8 + 4);
  f32x4 wa = *(const f32x4*)(Wg2 + li*8);
  f32x4 wb = *(const f32x4*)(Wg2 + li*8 + 4);
  const float vch[8]  = {va[0],va[1],va[2],va[3],vb[0],vb[1],vb[2],vb[3]};
  const float w2ch[8] = {wa[0],wa[1],wa[2],wa[3],wb[0],wb[1],wb[2],wb[3]};
  const float bg2v = bg2p[0];

  const int beg = bptr[gw*NSTRIPE], end = bptr[gw*NSTRIPE + NSTRIPE];
  float a0 = 0.f, a1 = 0.f, wsum = 0.f;

  for(int base = beg; base < end; base += 64){
    const int nb = min(64, end - base);

    float2 sc_c0, sc_c1; bf16x8 u_c0, u_c1;
    {
      const int i0 = (eq     < nb) ? eq     : 0;
      const int i1 = (4 + eq < nb) ? 4 + eq : 0;
      sc_c0 = scp[base + i0]; sc_c1 = scp[base + i1];
      u_c0 = *(const bf16x8*)&UH[(uint32_t)__float_as_int(sc_c0.y)*256u + li*8];
      u_c1 = *(const bf16x8*)&UH[(uint32_t)__float_as_int(sc_c1.y)*256u + li*8];
    }
    for(int q = 0; q < nb; q += 8){
      float2 sc_n0 = sc_c0, sc_n1 = sc_c1; bf16x8 u_n0 = u_c0, u_n1 = u_c1;
      if(q + 8 < nb){
        const int i0 = (q + 8  + eq < nb) ? q + 8  + eq : 0;
        const int i1 = (q + 12 + eq < nb) ? q + 12 + eq : 0;
        sc_n0 = scp[base + i0]; sc_n1 = scp[base + i1];
        u_n0 = *(const bf16x8*)&UH[(uint32_t)__float_as_int(sc_n0.y)*256u + li*8];
        u_n1 = *(const bf16x8*)&UH[(uint32_t)__float_as_int(sc_n1.y)*256u + li*8];
      }
      { // edge A: idx = q + eq
        union { bf16x8 v; uint32_t u32[4]; } uu; uu.v = u_c0;
        float tacc = 0.f;
        #pragma unroll
        for(int p = 0; p < 4; p++){
          const uint32_t w2b = uu.u32[p];
          tacc += fmaxf(bf16lo_to_f32(w2b) + vch[2*p],   0.f) * w2ch[2*p];
          tacc += fmaxf(bf16hi_to_f32(w2b) + vch[2*p+1], 0.f) * w2ch[2*p+1];
        }
        tacc = DPP_ADD(tacc, 0xB1);
        tacc = DPP_ADD(tacc, 0x4E);
        tacc = DPP_ADD(tacc, 0x141);
        tacc = DPP_ADD(tacc, 0x140);
        const float g = 1.f/(1.f + __expf(-(tacc + bg2v)));
        const int idx = q + eq;
        if(li == 0 && idx < nb) ws_s[wv][idx] = make_float2(sc_c0.x*g, sc_c0.y);
      }
      { // edge B: idx = q + 4 + eq
        union { bf16x8 v; uint32_t u32[4]; } uu; uu.v = u_c1;
        float tacc = 0.f;
        #pragma unroll
        for(int p = 0; p < 4; p++){
          const uint32_t w2b = uu.u32[p];
          tacc += fmaxf(bf16lo_to_f32(w2b) + vch[2*p],   0.f) * w2ch[2*p];
          tacc += fmaxf(bf16hi_to_f32(w2b) + vch[2*p+1], 0.f) * w2ch[2*p+1];
        }
        tacc = DPP_ADD(tacc, 0xB1);
        tacc = DPP_ADD(tacc, 0x4E);
        tacc = DPP_ADD(tacc, 0x141);
        tacc = DPP_ADD(tacc, 0x140);
        const float g = 1.f/(1.f + __expf(-(tacc + bg2v)));
        const int idx = q + 4 + eq;
        if(li == 0 && idx < nb) ws_s[wv][idx] = make_float2(sc_c1.x*g, sc_c1.y);
      }
      sc_c0 = sc_n0; sc_c1 = sc_n1; u_c0 = u_n0; u_c1 = u_n1;
    }

    #pragma unroll 8
    for(int j = 0; j < nb; j++){
      const float2 p = ws_s[wv][j];
      const float w  = p.x;
      const uint32_t s = (uint32_t)__float_as_int(p.y);
      const uint32_t hw = *(const uint32_t*)&UH[s*256u + 128u + lane*2];
      a0 += w*bf16lo_to_f32(hw);
      a1 += w*bf16hi_to_f32(hw);
      wsum += w;
    }
  }
  const float inv = 1.f/(wsum + EPSV);
  const size_t o = (size_t)gw*128 + lane*2;
  *(f32x2*)&out_f32[o] = (f32x2){a0*inv, a1*inv};
}

// ---------------- launch ----------------

extern "C" void kernel_launch(void* const* d_in, const int* in_sizes, int n_in,
                              void* d_out, int out_size, void* d_ws, size_t ws_size,
                              hipStream_t stream) {
  (void)in_sizes; (void)n_in; (void)out_size; (void)ws_size;
  const float* X      = (const float*)d_in[0];
  const int*   src    = (const int*)d_in[1];
  const int*   dst    = (const int*)d_in[2];
  const float* base_w = (const float*)d_in[3];
  const float* W1     = (const float*)d_in[4];
  const float* b1     = (const float*)d_in[5];
  const float* W2     = (const float*)d_in[6];
  const float* b2     = (const float*)d_in[7];
  const float* Wg1    = (const float*)d_in[8];
  const float* bg1    = (const float*)d_in[9];
  const float* Wg2    = (const float*)d_in[10];
  const float* bg2    = (const float*)d_in[11];
  const float* rho    = (const float*)d_in[12];

  char* ws = (char*)d_ws;
  size_t off = 0;
  auto alloc = [&](size_t bytes)->char*{ char* p = ws + off; off += (bytes + 255) & ~(size_t)255; return p; };
  unsigned short* W1T      = (unsigned short*)alloc((size_t)1024*128*2);
  unsigned short* W2T      = (unsigned short*)alloc((size_t)128*128*2);
  unsigned short* Wg1T     = (unsigned short*)alloc((size_t)256*128*2);
  int*            rank     = (int*)alloc((size_t)EE*4);
  float2*         scp      = (float2*)alloc((size_t)EE*8);
  int*            bptr     = (int*)alloc((size_t)(NBUCK+1)*4);
  int*            counts   = (int*)alloc((size_t)NBUCK*4);
  int*            lexcl    = (int*)alloc((size_t)NBUCK*4);
  int*            bsum     = (int*)alloc((size_t)SCAN_BLKS*4);
  int*            bexcl    = (int*)alloc((size_t)SCAN_BLKS*4);
  unsigned short* h1       = (unsigned short*)alloc((size_t)NN*128*2);
  unsigned short* UH       = (unsigned short*)alloc((size_t)NN*256*2);
  float*          Vf       = (float*)alloc((size_t)NN*128*4);
  float*          hf_B     = (float*)alloc((size_t)NN*128*4);

  hipMemsetAsync(counts, 0, (size_t)NBUCK*4, stream);
  k_prep_all<<<704, 256, 0, stream>>>(W1, W2, Wg1, W1T, W2T, Wg1T);

  // fused: encoder GEMM1 + histogram (independent work, overlapped)
  k_enc1_hist<<<ENC_BLKS + EDGE_BLKS, 256, 0, stream>>>(
      X, W1T, b1, h1, src, dst, counts, rank);

  k_scan1<<<SCAN_BLKS, 256, 0, stream>>>(counts, lexcl, bsum);
  k_scan_mid<<<1, 1024, 0, stream>>>(bsum, bexcl);
  k_scan3<<<SCAN_BLKS, 256, 0, stream>>>(lexcl, bexcl, bptr);

  // fused: uvA (layer-1 node tables) + CSR fill (independent, overlapped)
  k_uvA_fill<<<UV_BLKS + EDGE_BLKS, 256, 0, stream>>>(
      h1, W2T, b2, Wg1T, bg1, UH, Vf, src, dst, base_w, rho, bptr, rank, scp);

  // layer 1
  k_gate_agg<<<12500, 256, 0, stream>>>(UH, Vf, bptr, scp, Wg2, bg2, hf_B);
  // layer 2
  k_uvB<<<782, 256, 0, stream>>>(hf_B, Wg1T, bg1, UH, Vf);
  k_gate_agg<<<12500, 256, 0, stream>>>(UH, Vf, bptr, scp, Wg2, bg2, (float*)d_out);
}